// Round 1
// baseline (1091.699 us; speedup 1.0000x reference)
//
#include <hip/hip_runtime.h>
#include <cstdint>
#include <cstddef>

#define SLOPE 0.2f

// ---------------- CSR build ----------------

__global__ void k_count(const int* __restrict__ dst, int* __restrict__ counts, int E) {
  int e = blockIdx.x * 256 + threadIdx.x;
  if (e < E) atomicAdd(&counts[dst[e]], 1);
}

// per-block exclusive scan over 2048 elements (256 threads x 8)
__global__ void k_scan1(const int* __restrict__ counts, int* __restrict__ excl,
                        int* __restrict__ bsums, int N) {
  __shared__ int lds[256];
  int tid = threadIdx.x;
  int base = blockIdx.x * 2048 + tid * 8;
  int v[8];
  int ts = 0;
#pragma unroll
  for (int i = 0; i < 8; i++) {
    int idx = base + i;
    int t = (idx < N) ? counts[idx] : 0;
    v[i] = ts;         // exclusive within thread
    ts += t;
  }
  lds[tid] = ts;
  __syncthreads();
  for (int off = 1; off < 256; off <<= 1) {
    int t = (tid >= off) ? lds[tid - off] : 0;
    __syncthreads();
    lds[tid] += t;
    __syncthreads();
  }
  int texcl = (tid > 0) ? lds[tid - 1] : 0;
#pragma unroll
  for (int i = 0; i < 8; i++) {
    int idx = base + i;
    if (idx < N) excl[idx] = texcl + v[i];
  }
  if (tid == 255) bsums[blockIdx.x] = lds[255];
}

__global__ void k_scan2(int* bsums, int nb) {
  __shared__ int lds[256];
  int tid = threadIdx.x;
  int v = (tid < nb) ? bsums[tid] : 0;
  lds[tid] = v;
  __syncthreads();
  for (int off = 1; off < 256; off <<= 1) {
    int t = (tid >= off) ? lds[tid - off] : 0;
    __syncthreads();
    lds[tid] += t;
    __syncthreads();
  }
  if (tid < nb) bsums[tid] = (tid > 0) ? lds[tid - 1] : 0;
}

__global__ void k_scan3(int* __restrict__ excl, int* __restrict__ cursor,
                        const int* __restrict__ bsums, int N) {
  int tid = threadIdx.x;
  int off = bsums[blockIdx.x];
  int base = blockIdx.x * 2048 + tid * 8;
#pragma unroll
  for (int i = 0; i < 8; i++) {
    int idx = base + i;
    if (idx < N) {
      int val = excl[idx] + off;
      excl[idx] = val;
      cursor[idx] = val;
    }
  }
}

__global__ void k_fill(const int* __restrict__ dst, int* __restrict__ cursor,
                       int* __restrict__ csr, int E) {
  int e = blockIdx.x * 256 + threadIdx.x;
  if (e < E) {
    int pos = atomicAdd(&cursor[dst[e]], 1);
    csr[pos] = e;
  }
}

// ---------------- GEMM: C[M,128] = A[M,K] @ W[128,K]^T ----------------
// 128x128 block tile, BK=32, 256 threads, 8x8 per-thread register tile.

__global__ __launch_bounds__(256) void k_gemm(const float* __restrict__ A,
                                              const float* __restrict__ W,
                                              float* __restrict__ C,
                                              int M, int K) {
  __shared__ float As[32][132];
  __shared__ float Bs[32][132];
  const int tid = threadIdx.x;
  const int bm = blockIdx.x * 128;
  const int tx = tid & 15, ty = tid >> 4;
  const int colg = tx * 8, rowg = ty * 8;
  float acc[8][8] = {{0.f}};

  for (int k0 = 0; k0 < K; k0 += 32) {
#pragma unroll
    for (int r = 0; r < 4; r++) {
      int idx = r * 256 + tid;
      int m = idx >> 3;
      int kg = (idx & 7) * 4;
      float4 av = make_float4(0.f, 0.f, 0.f, 0.f);
      if (bm + m < M) av = *(const float4*)&A[(size_t)(bm + m) * K + k0 + kg];
      As[kg + 0][m] = av.x; As[kg + 1][m] = av.y;
      As[kg + 2][m] = av.z; As[kg + 3][m] = av.w;
      float4 wv = *(const float4*)&W[(size_t)m * K + k0 + kg];
      Bs[kg + 0][m] = wv.x; Bs[kg + 1][m] = wv.y;
      Bs[kg + 2][m] = wv.z; Bs[kg + 3][m] = wv.w;
    }
    __syncthreads();
#pragma unroll
    for (int kk = 0; kk < 32; kk++) {
      float4 a0 = *(const float4*)&As[kk][rowg];
      float4 a1 = *(const float4*)&As[kk][rowg + 4];
      float4 b0 = *(const float4*)&Bs[kk][colg];
      float4 b1 = *(const float4*)&Bs[kk][colg + 4];
      float a[8] = {a0.x, a0.y, a0.z, a0.w, a1.x, a1.y, a1.z, a1.w};
      float b[8] = {b0.x, b0.y, b0.z, b0.w, b1.x, b1.y, b1.z, b1.w};
#pragma unroll
      for (int i = 0; i < 8; i++)
#pragma unroll
        for (int j = 0; j < 8; j++)
          acc[i][j] = fmaf(a[i], b[j], acc[i][j]);
    }
    __syncthreads();
  }
#pragma unroll
  for (int i = 0; i < 8; i++) {
    int grow = bm + rowg + i;
    if (grow < M) {
      float4 o0 = make_float4(acc[i][0], acc[i][1], acc[i][2], acc[i][3]);
      float4 o1 = make_float4(acc[i][4], acc[i][5], acc[i][6], acc[i][7]);
      *(float4*)&C[(size_t)grow * 128 + colg] = o0;
      *(float4*)&C[(size_t)grow * 128 + colg + 4] = o1;
    }
  }
}

// ---------------- attention scalars: a_src/a_dst [N,4] ----------------
// 2 nodes per 256-thread block; 32-lane shuffle reduction per head.

__global__ __launch_bounds__(256) void k_att(const float* __restrict__ xp,
                                             const float* __restrict__ att_src,
                                             const float* __restrict__ att_dst,
                                             float* __restrict__ a_src,
                                             float* __restrict__ a_dst, int N) {
  int tid = threadIdx.x;
  int n = blockIdx.x * 2 + (tid >> 7);
  int c = tid & 127;
  int h = c >> 5, cc = c & 31;
  if (n >= N) return;
  float v = xp[n * 128 + c];
  float vs = v * att_src[h * 32 + cc];
  float vd = v * att_dst[h * 32 + cc];
#pragma unroll
  for (int off = 16; off >= 1; off >>= 1) {
    vs += __shfl_xor(vs, off);
    vd += __shfl_xor(vd, off);
  }
  if (cc == 0) {
    a_src[n * 4 + h] = vs;
    a_dst[n * 4 + h] = vd;
  }
}

// ---------------- per-edge logits e[E,4] (leaky-relu applied) ----------------

__global__ void k_edge(const int* __restrict__ src, const int* __restrict__ dst,
                       const float* __restrict__ a_src, const float* __restrict__ a_dst,
                       float* __restrict__ e_buf, int E) {
  int e = blockIdx.x * 256 + threadIdx.x;
  if (e >= E) return;
  int s = src[e], d = dst[e];
  float4 as4 = *(const float4*)&a_src[s * 4];
  float4 ad4 = *(const float4*)&a_dst[d * 4];
  float4 ev;
  ev.x = as4.x + ad4.x; ev.x = (ev.x > 0.f) ? ev.x : SLOPE * ev.x;
  ev.y = as4.y + ad4.y; ev.y = (ev.y > 0.f) ? ev.y : SLOPE * ev.y;
  ev.z = as4.z + ad4.z; ev.z = (ev.z > 0.f) ? ev.z : SLOPE * ev.z;
  ev.w = as4.w + ad4.w; ev.w = (ev.w > 0.f) ? ev.w : SLOPE * ev.w;
  *(float4*)&e_buf[e * 4] = ev;
}

// ---------------- per-node softmax + aggregation ----------------
// 1 block (128 threads) per node; thread c owns output channel c.

template <bool RELU>
__global__ __launch_bounds__(128) void k_agg(const float* __restrict__ xp,
                                             const float* __restrict__ e_buf,
                                             const int* __restrict__ csr,
                                             const int* __restrict__ indptr,
                                             const int* __restrict__ counts,
                                             const int* __restrict__ src,
                                             const float* __restrict__ bias,
                                             float* __restrict__ out, int N) {
  int n = blockIdx.x;
  int c = threadIdx.x;
  int h = c >> 5;
  int deg = counts[n];
  int start = indptr[n];
  float m = -INFINITY;
  for (int i = 0; i < deg; i++) {
    int eid = csr[start + i];
    m = fmaxf(m, e_buf[eid * 4 + h]);
  }
  float s = 0.f;
  for (int i = 0; i < deg; i++) {
    int eid = csr[start + i];
    s += __expf(e_buf[eid * 4 + h] - m);
  }
  float inv = 1.f / (s + 1e-16f);
  float acc = 0.f;
  for (int i = 0; i < deg; i++) {
    int eid = csr[start + i];
    float al = __expf(e_buf[eid * 4 + h] - m) * inv;
    acc = fmaf(xp[src[eid] * 128 + c], al, acc);
  }
  float o = acc + bias[c];
  if (RELU) o = fmaxf(o, 0.f);
  out[n * 128 + c] = o;
}

// ---------------- launch ----------------

extern "C" void kernel_launch(void* const* d_in, const int* in_sizes, int n_in,
                              void* d_out, int out_size, void* d_ws, size_t ws_size,
                              hipStream_t stream) {
  const float* x   = (const float*)d_in[0];
  const int*   ei  = (const int*)d_in[1];
  const float* W0  = (const float*)d_in[2];
  const float* as0 = (const float*)d_in[3];
  const float* ad0 = (const float*)d_in[4];
  const float* b0  = (const float*)d_in[5];
  const float* W1  = (const float*)d_in[6];
  const float* as1 = (const float*)d_in[7];
  const float* ad1 = (const float*)d_in[8];
  const float* b1  = (const float*)d_in[9];

  const int N = in_sizes[0] / 256;   // 100000
  const int E = in_sizes[1] / 2;     // 800000
  const int* src = ei;
  const int* dst = ei + E;

  char* ws = (char*)d_ws;
  size_t off = 0;
  auto alloc = [&](size_t bytes) -> void* {
    void* p = ws + off;
    off += (bytes + 255) & ~(size_t)255;
    return p;
  };
  float* xp     = (float*)alloc((size_t)N * 128 * 4);
  float* hbuf   = (float*)alloc((size_t)N * 128 * 4);
  float* a_src  = (float*)alloc((size_t)N * 4 * 4);
  float* a_dst  = (float*)alloc((size_t)N * 4 * 4);
  float* e_buf  = (float*)alloc((size_t)E * 4 * 4);
  int*   counts = (int*)alloc((size_t)N * 4);
  int*   indptr = (int*)alloc((size_t)N * 4);
  int*   cursor = (int*)alloc((size_t)N * 4);
  int*   csr    = (int*)alloc((size_t)E * 4);
  int*   bsums  = (int*)alloc(256 * 4);

  // ---- CSR build (by dst) ----
  hipMemsetAsync(counts, 0, (size_t)N * 4, stream);
  int eb = (E + 255) / 256;
  int nb = (N + 2047) / 2048;
  k_count<<<eb, 256, 0, stream>>>(dst, counts, E);
  k_scan1<<<nb, 256, 0, stream>>>(counts, indptr, bsums, N);
  k_scan2<<<1, 256, 0, stream>>>(bsums, nb);
  k_scan3<<<nb, 256, 0, stream>>>(indptr, cursor, bsums, N);
  k_fill<<<eb, 256, 0, stream>>>(dst, cursor, csr, E);

  int gb = (N + 127) / 128;
  int ab = (N + 1) / 2;

  // ---- layer 0 ----
  k_gemm<<<gb, 256, 0, stream>>>(x, W0, xp, N, 256);
  k_att<<<ab, 256, 0, stream>>>(xp, as0, ad0, a_src, a_dst, N);
  k_edge<<<eb, 256, 0, stream>>>(src, dst, a_src, a_dst, e_buf, E);
  k_agg<true><<<N, 128, 0, stream>>>(xp, e_buf, csr, indptr, counts, src, b0, hbuf, N);

  // ---- layer 1 ----
  k_gemm<<<gb, 256, 0, stream>>>(hbuf, W1, xp, N, 128);
  k_att<<<ab, 256, 0, stream>>>(xp, as1, ad1, a_src, a_dst, N);
  k_edge<<<eb, 256, 0, stream>>>(src, dst, a_src, a_dst, e_buf, E);
  k_agg<false><<<N, 128, 0, stream>>>(xp, e_buf, csr, indptr, counts, src, b1,
                                      (float*)d_out, N);
}

// Round 2
// 523.205 us; speedup vs baseline: 2.0866x; 2.0866x over previous
//
#include <hip/hip_runtime.h>
#include <cstdint>
#include <cstddef>

#define SLOPE 0.2f

// ---------------- CSR build ----------------

__global__ void k_count(const int* __restrict__ dst, int* __restrict__ counts, int E) {
  int e = blockIdx.x * 256 + threadIdx.x;
  if (e < E) atomicAdd(&counts[dst[e]], 1);
}

// per-block exclusive scan over 2048 elements (256 threads x 8)
__global__ void k_scan1(const int* __restrict__ counts, int* __restrict__ excl,
                        int* __restrict__ bsums, int N) {
  __shared__ int lds[256];
  int tid = threadIdx.x;
  int base = blockIdx.x * 2048 + tid * 8;
  int v[8];
  int ts = 0;
#pragma unroll
  for (int i = 0; i < 8; i++) {
    int idx = base + i;
    int t = (idx < N) ? counts[idx] : 0;
    v[i] = ts;         // exclusive within thread
    ts += t;
  }
  lds[tid] = ts;
  __syncthreads();
  for (int off = 1; off < 256; off <<= 1) {
    int t = (tid >= off) ? lds[tid - off] : 0;
    __syncthreads();
    lds[tid] += t;
    __syncthreads();
  }
  int texcl = (tid > 0) ? lds[tid - 1] : 0;
#pragma unroll
  for (int i = 0; i < 8; i++) {
    int idx = base + i;
    if (idx < N) excl[idx] = texcl + v[i];
  }
  if (tid == 255) bsums[blockIdx.x] = lds[255];
}

__global__ void k_scan2(int* bsums, int nb) {
  __shared__ int lds[256];
  int tid = threadIdx.x;
  int v = (tid < nb) ? bsums[tid] : 0;
  lds[tid] = v;
  __syncthreads();
  for (int off = 1; off < 256; off <<= 1) {
    int t = (tid >= off) ? lds[tid - off] : 0;
    __syncthreads();
    lds[tid] += t;
    __syncthreads();
  }
  if (tid < nb) bsums[tid] = (tid > 0) ? lds[tid - 1] : 0;
}

__global__ void k_scan3(int* __restrict__ excl, int* __restrict__ cursor,
                        const int* __restrict__ bsums, int N) {
  int tid = threadIdx.x;
  int off = bsums[blockIdx.x];
  int base = blockIdx.x * 2048 + tid * 8;
#pragma unroll
  for (int i = 0; i < 8; i++) {
    int idx = base + i;
    if (idx < N) {
      int val = excl[idx] + off;
      excl[idx] = val;
      cursor[idx] = val;
    }
  }
}

// scatter src/dst into dst-sorted position space
__global__ void k_fill(const int* __restrict__ src, const int* __restrict__ dst,
                       int* __restrict__ cursor,
                       int* __restrict__ src_sorted, int* __restrict__ dst_sorted,
                       int E) {
  int e = blockIdx.x * 256 + threadIdx.x;
  if (e < E) {
    int d = dst[e];
    int pos = atomicAdd(&cursor[d], 1);
    src_sorted[pos] = src[e];
    dst_sorted[pos] = d;
  }
}

// ---------------- GEMM: C[M,128] = A[M,K] @ W[128,K]^T ----------------
// 128x128 block tile, BK=32, 256 threads, 8x8 per-thread register tile.

__global__ __launch_bounds__(256) void k_gemm(const float* __restrict__ A,
                                              const float* __restrict__ W,
                                              float* __restrict__ C,
                                              int M, int K) {
  __shared__ float As[32][132];
  __shared__ float Bs[32][132];
  const int tid = threadIdx.x;
  const int bm = blockIdx.x * 128;
  const int tx = tid & 15, ty = tid >> 4;
  const int colg = tx * 8, rowg = ty * 8;
  float acc[8][8] = {{0.f}};

  for (int k0 = 0; k0 < K; k0 += 32) {
#pragma unroll
    for (int r = 0; r < 4; r++) {
      int idx = r * 256 + tid;
      int m = idx >> 3;
      int kg = (idx & 7) * 4;
      float4 av = make_float4(0.f, 0.f, 0.f, 0.f);
      if (bm + m < M) av = *(const float4*)&A[(size_t)(bm + m) * K + k0 + kg];
      As[kg + 0][m] = av.x; As[kg + 1][m] = av.y;
      As[kg + 2][m] = av.z; As[kg + 3][m] = av.w;
      float4 wv = *(const float4*)&W[(size_t)m * K + k0 + kg];
      Bs[kg + 0][m] = wv.x; Bs[kg + 1][m] = wv.y;
      Bs[kg + 2][m] = wv.z; Bs[kg + 3][m] = wv.w;
    }
    __syncthreads();
#pragma unroll
    for (int kk = 0; kk < 32; kk++) {
      float4 a0 = *(const float4*)&As[kk][rowg];
      float4 a1 = *(const float4*)&As[kk][rowg + 4];
      float4 b0 = *(const float4*)&Bs[kk][colg];
      float4 b1 = *(const float4*)&Bs[kk][colg + 4];
      float a[8] = {a0.x, a0.y, a0.z, a0.w, a1.x, a1.y, a1.z, a1.w};
      float b[8] = {b0.x, b0.y, b0.z, b0.w, b1.x, b1.y, b1.z, b1.w};
#pragma unroll
      for (int i = 0; i < 8; i++)
#pragma unroll
        for (int j = 0; j < 8; j++)
          acc[i][j] = fmaf(a[i], b[j], acc[i][j]);
    }
    __syncthreads();
  }
#pragma unroll
  for (int i = 0; i < 8; i++) {
    int grow = bm + rowg + i;
    if (grow < M) {
      float4 o0 = make_float4(acc[i][0], acc[i][1], acc[i][2], acc[i][3]);
      float4 o1 = make_float4(acc[i][4], acc[i][5], acc[i][6], acc[i][7]);
      *(float4*)&C[(size_t)grow * 128 + colg] = o0;
      *(float4*)&C[(size_t)grow * 128 + colg + 4] = o1;
    }
  }
}

// ---------------- attention scalars: a_src/a_dst [N,4] ----------------

__global__ __launch_bounds__(256) void k_att(const float* __restrict__ xp,
                                             const float* __restrict__ att_src,
                                             const float* __restrict__ att_dst,
                                             float* __restrict__ a_src,
                                             float* __restrict__ a_dst, int N) {
  int tid = threadIdx.x;
  int n = blockIdx.x * 2 + (tid >> 7);
  int c = tid & 127;
  int h = c >> 5, cc = c & 31;
  if (n >= N) return;
  float v = xp[n * 128 + c];
  float vs = v * att_src[h * 32 + cc];
  float vd = v * att_dst[h * 32 + cc];
#pragma unroll
  for (int off = 16; off >= 1; off >>= 1) {
    vs += __shfl_xor(vs, off);
    vd += __shfl_xor(vd, off);
  }
  if (cc == 0) {
    a_src[n * 4 + h] = vs;
    a_dst[n * 4 + h] = vd;
  }
}

// ---------------- per-position logits e_sorted[p,4] (leaky-relu applied) ----------------

__global__ void k_edge(const int* __restrict__ ss, const int* __restrict__ ds,
                       const float* __restrict__ a_src, const float* __restrict__ a_dst,
                       float* __restrict__ e_sorted, int E) {
  int p = blockIdx.x * 256 + threadIdx.x;
  if (p >= E) return;
  int s = ss[p], d = ds[p];
  float4 as4 = *(const float4*)&a_src[s * 4];
  float4 ad4 = *(const float4*)&a_dst[d * 4];
  float4 ev;
  ev.x = as4.x + ad4.x; ev.x = (ev.x > 0.f) ? ev.x : SLOPE * ev.x;
  ev.y = as4.y + ad4.y; ev.y = (ev.y > 0.f) ? ev.y : SLOPE * ev.y;
  ev.z = as4.z + ad4.z; ev.z = (ev.z > 0.f) ? ev.z : SLOPE * ev.z;
  ev.w = as4.w + ad4.w; ev.w = (ev.w > 0.f) ? ev.w : SLOPE * ev.w;
  *(float4*)&e_sorted[p * 4] = ev;
}

// ---------------- per-node softmax + aggregation (2 passes, unrolled x4) ----------------
// 1 block (128 threads) per node; thread c owns output channel c. All reads
// of e_sorted/src_sorted are sequential in position space (no csr indirection).

template <bool RELU>
__global__ __launch_bounds__(128) void k_agg(const float* __restrict__ xp,
                                             const float* __restrict__ e_sorted,
                                             const int* __restrict__ src_sorted,
                                             const int* __restrict__ indptr,
                                             const int* __restrict__ counts,
                                             const float* __restrict__ bias,
                                             float* __restrict__ out, int N) {
  int n = blockIdx.x;
  int c = threadIdx.x;
  int h = c >> 5;
  int deg = counts[n];
  int start = indptr[n];
  const float* eb = e_sorted + (size_t)start * 4 + h;
  const int* sp = src_sorted + start;

  // pass 1: segment max (4 independent loads in flight)
  float m0 = -INFINITY, m1 = -INFINITY, m2 = -INFINITY, m3 = -INFINITY;
  int i = 0;
  for (; i + 4 <= deg; i += 4) {
    float a = eb[(i + 0) * 4], b = eb[(i + 1) * 4];
    float d = eb[(i + 2) * 4], e = eb[(i + 3) * 4];
    m0 = fmaxf(m0, a); m1 = fmaxf(m1, b); m2 = fmaxf(m2, d); m3 = fmaxf(m3, e);
  }
  for (; i < deg; i++) m0 = fmaxf(m0, eb[i * 4]);
  float m = fmaxf(fmaxf(m0, m1), fmaxf(m2, m3));

  // pass 2: fused exp + sum + gather-accumulate (4 xp rows in flight)
  float s = 0.f, acc = 0.f;
  i = 0;
  for (; i + 4 <= deg; i += 4) {
    int s0 = sp[i], s1 = sp[i + 1], s2 = sp[i + 2], s3 = sp[i + 3];
    float e0 = eb[(i + 0) * 4], e1 = eb[(i + 1) * 4];
    float e2 = eb[(i + 2) * 4], e3 = eb[(i + 3) * 4];
    float v0 = xp[(size_t)s0 * 128 + c];
    float v1 = xp[(size_t)s1 * 128 + c];
    float v2 = xp[(size_t)s2 * 128 + c];
    float v3 = xp[(size_t)s3 * 128 + c];
    float x0 = __expf(e0 - m), x1 = __expf(e1 - m);
    float x2 = __expf(e2 - m), x3 = __expf(e3 - m);
    s += x0 + x1 + x2 + x3;
    acc = fmaf(v0, x0, acc); acc = fmaf(v1, x1, acc);
    acc = fmaf(v2, x2, acc); acc = fmaf(v3, x3, acc);
  }
  for (; i < deg; i++) {
    int s0 = sp[i];
    float x0 = __expf(eb[i * 4] - m);
    s += x0;
    acc = fmaf(xp[(size_t)s0 * 128 + c], x0, acc);
  }

  float inv = 1.f / (s + 1e-16f);
  float o = acc * inv + bias[c];
  if (RELU) o = fmaxf(o, 0.f);
  out[(size_t)n * 128 + c] = o;
}

// ---------------- launch ----------------

extern "C" void kernel_launch(void* const* d_in, const int* in_sizes, int n_in,
                              void* d_out, int out_size, void* d_ws, size_t ws_size,
                              hipStream_t stream) {
  const float* x   = (const float*)d_in[0];
  const int*   ei  = (const int*)d_in[1];
  const float* W0  = (const float*)d_in[2];
  const float* as0 = (const float*)d_in[3];
  const float* ad0 = (const float*)d_in[4];
  const float* b0  = (const float*)d_in[5];
  const float* W1  = (const float*)d_in[6];
  const float* as1 = (const float*)d_in[7];
  const float* ad1 = (const float*)d_in[8];
  const float* b1  = (const float*)d_in[9];

  const int N = in_sizes[0] / 256;   // 100000
  const int E = in_sizes[1] / 2;     // 800000
  const int* src = ei;
  const int* dst = ei + E;

  char* ws = (char*)d_ws;
  size_t off = 0;
  auto alloc = [&](size_t bytes) -> void* {
    void* p = ws + off;
    off += (bytes + 255) & ~(size_t)255;
    return p;
  };
  float* xp     = (float*)alloc((size_t)N * 128 * 4);
  float* hbuf   = (float*)alloc((size_t)N * 128 * 4);
  float* a_src  = (float*)alloc((size_t)N * 4 * 4);
  float* a_dst  = (float*)alloc((size_t)N * 4 * 4);
  float* e_sort = (float*)alloc((size_t)E * 4 * 4);
  int*   counts = (int*)alloc((size_t)N * 4);
  int*   indptr = (int*)alloc((size_t)N * 4);
  int*   cursor = (int*)alloc((size_t)N * 4);
  int*   ssort  = (int*)alloc((size_t)E * 4);
  int*   dsort  = (int*)alloc((size_t)E * 4);
  int*   bsums  = (int*)alloc(256 * 4);

  // ---- CSR build (by dst) ----
  hipMemsetAsync(counts, 0, (size_t)N * 4, stream);
  int eb = (E + 255) / 256;
  int nb = (N + 2047) / 2048;
  k_count<<<eb, 256, 0, stream>>>(dst, counts, E);
  k_scan1<<<nb, 256, 0, stream>>>(counts, indptr, bsums, N);
  k_scan2<<<1, 256, 0, stream>>>(bsums, nb);
  k_scan3<<<nb, 256, 0, stream>>>(indptr, cursor, bsums, N);
  k_fill<<<eb, 256, 0, stream>>>(src, dst, cursor, ssort, dsort, E);

  int gb = (N + 127) / 128;
  int ab = (N + 1) / 2;

  // ---- layer 0 ----
  k_gemm<<<gb, 256, 0, stream>>>(x, W0, xp, N, 256);
  k_att<<<ab, 256, 0, stream>>>(xp, as0, ad0, a_src, a_dst, N);
  k_edge<<<eb, 256, 0, stream>>>(ssort, dsort, a_src, a_dst, e_sort, E);
  k_agg<true><<<N, 128, 0, stream>>>(xp, e_sort, ssort, indptr, counts, b0, hbuf, N);

  // ---- layer 1 ----
  k_gemm<<<gb, 256, 0, stream>>>(hbuf, W1, xp, N, 128);
  k_att<<<ab, 256, 0, stream>>>(xp, as1, ad1, a_src, a_dst, N);
  k_edge<<<eb, 256, 0, stream>>>(ssort, dsort, a_src, a_dst, e_sort, E);
  k_agg<false><<<N, 128, 0, stream>>>(xp, e_sort, ssort, indptr, counts, b1,
                                      (float*)d_out, N);
}

// Round 3
// 399.635 us; speedup vs baseline: 2.7317x; 1.3092x over previous
//
#include <hip/hip_runtime.h>
#include <hip/hip_bf16.h>
#include <cstdint>
#include <cstddef>
#include <type_traits>

#define SLOPE 0.2f

typedef __attribute__((ext_vector_type(8))) short short8v;
typedef __attribute__((ext_vector_type(4))) float float4v;

__device__ inline ushort f2bf(float f) {
  uint u = __float_as_uint(f);
  uint r = (u + 0x7FFFu + ((u >> 16) & 1u)) >> 16;
  return (ushort)r;
}
__device__ inline float bf2f(ushort u) {
  return __uint_as_float(((uint)u) << 16);
}

// ---------------- CSR build ----------------

__global__ void k_count(const int* __restrict__ dst, int* __restrict__ counts, int E) {
  int e = blockIdx.x * 256 + threadIdx.x;
  if (e < E) atomicAdd(&counts[dst[e]], 1);
}

__global__ void k_scan1(const int* __restrict__ counts, int* __restrict__ excl,
                        int* __restrict__ bsums, int N) {
  __shared__ int lds[256];
  int tid = threadIdx.x;
  int base = blockIdx.x * 2048 + tid * 8;
  int v[8];
  int ts = 0;
#pragma unroll
  for (int i = 0; i < 8; i++) {
    int idx = base + i;
    int t = (idx < N) ? counts[idx] : 0;
    v[i] = ts;
    ts += t;
  }
  lds[tid] = ts;
  __syncthreads();
  for (int off = 1; off < 256; off <<= 1) {
    int t = (tid >= off) ? lds[tid - off] : 0;
    __syncthreads();
    lds[tid] += t;
    __syncthreads();
  }
  int texcl = (tid > 0) ? lds[tid - 1] : 0;
#pragma unroll
  for (int i = 0; i < 8; i++) {
    int idx = base + i;
    if (idx < N) excl[idx] = texcl + v[i];
  }
  if (tid == 255) bsums[blockIdx.x] = lds[255];
}

__global__ void k_scan2(int* bsums, int nb) {
  __shared__ int lds[256];
  int tid = threadIdx.x;
  int v = (tid < nb) ? bsums[tid] : 0;
  lds[tid] = v;
  __syncthreads();
  for (int off = 1; off < 256; off <<= 1) {
    int t = (tid >= off) ? lds[tid - off] : 0;
    __syncthreads();
    lds[tid] += t;
    __syncthreads();
  }
  if (tid < nb) bsums[tid] = (tid > 0) ? lds[tid - 1] : 0;
}

__global__ void k_scan3(int* __restrict__ excl, int* __restrict__ cursor,
                        const int* __restrict__ bsums, int N) {
  int tid = threadIdx.x;
  int off = bsums[blockIdx.x];
  int base = blockIdx.x * 2048 + tid * 8;
#pragma unroll
  for (int i = 0; i < 8; i++) {
    int idx = base + i;
    if (idx < N) {
      int val = excl[idx] + off;
      excl[idx] = val;
      cursor[idx] = val;
    }
  }
}

__global__ void k_fill(const int* __restrict__ src, const int* __restrict__ dst,
                       int* __restrict__ cursor,
                       int* __restrict__ src_sorted, int* __restrict__ dst_sorted,
                       int E) {
  int e = blockIdx.x * 256 + threadIdx.x;
  if (e < E) {
    int d = dst[e];
    int pos = atomicAdd(&cursor[d], 1);
    src_sorted[pos] = src[e];
    dst_sorted[pos] = d;
  }
}

// ---------------- MFMA GEMM: C[M,128] = A[M,K] @ W[128,K]^T ----------------
// 128x128 tile, BK=32, 256 threads (4 waves). A,W staged to LDS as bf16
// (converted in-flight). mfma_f32_16x16x32_bf16; C/D: col=lane&15,
// row=(lane>>4)*4+reg (verified mapping). LDS rows padded to 40 ushorts.

template <typename AT, typename CT>
__global__ __launch_bounds__(256) void k_gemm_mfma(const AT* __restrict__ A,
                                                   const float* __restrict__ W,
                                                   CT* __restrict__ C,
                                                   int M, int K) {
  __shared__ ushort As[128 * 40];
  __shared__ ushort Ws[128 * 40];
  const int tid = threadIdx.x;
  const int wave = tid >> 6, lane = tid & 63;
  const int bm = blockIdx.x * 128;
  const int r = tid >> 1;            // staging row 0..127
  const int cb = (tid & 1) * 16;     // staging col base {0,16}
  const int fr = lane & 15, fq = lane >> 4;
  float4v acc[2][8] = {};

  for (int k0 = 0; k0 < K; k0 += 32) {
    const bool valid = (bm + r) < M;
    if constexpr (std::is_same<AT, float>::value) {
      const float* ap = A + (size_t)(bm + r) * K + k0 + cb;
#pragma unroll
      for (int i = 0; i < 4; i++) {
        float4 v = valid ? *(const float4*)(ap + i * 4) : make_float4(0.f, 0.f, 0.f, 0.f);
        ushort4 pk;
        pk.x = f2bf(v.x); pk.y = f2bf(v.y); pk.z = f2bf(v.z); pk.w = f2bf(v.w);
        *(ushort4*)&As[r * 40 + cb + i * 4] = pk;
      }
    } else {
      const ushort* ap = (const ushort*)A + (size_t)(bm + r) * K + k0 + cb;
#pragma unroll
      for (int i = 0; i < 2; i++) {
        uint4 v = valid ? *(const uint4*)(ap + i * 8) : make_uint4(0, 0, 0, 0);
        *(uint4*)&As[r * 40 + cb + i * 8] = v;
      }
    }
    {
      const float* wp = W + (size_t)r * K + k0 + cb;
#pragma unroll
      for (int i = 0; i < 4; i++) {
        float4 v = *(const float4*)(wp + i * 4);
        ushort4 pk;
        pk.x = f2bf(v.x); pk.y = f2bf(v.y); pk.z = f2bf(v.z); pk.w = f2bf(v.w);
        *(ushort4*)&Ws[r * 40 + cb + i * 4] = pk;
      }
    }
    __syncthreads();
    short8v af[2];
    short8v bfr[8];
#pragma unroll
    for (int s = 0; s < 2; s++)
      af[s] = *(const short8v*)&As[(wave * 32 + s * 16 + fr) * 40 + fq * 8];
#pragma unroll
    for (int t = 0; t < 8; t++)
      bfr[t] = *(const short8v*)&Ws[(t * 16 + fr) * 40 + fq * 8];
#pragma unroll
    for (int s = 0; s < 2; s++)
#pragma unroll
      for (int t = 0; t < 8; t++)
        acc[s][t] = __builtin_amdgcn_mfma_f32_16x16x32_bf16(af[s], bfr[t], acc[s][t], 0, 0, 0);
    __syncthreads();
  }

#pragma unroll
  for (int s = 0; s < 2; s++) {
#pragma unroll
    for (int j = 0; j < 4; j++) {
      int row = bm + wave * 32 + s * 16 + fq * 4 + j;
      if (row < M) {
#pragma unroll
        for (int t = 0; t < 8; t++) {
          float v = acc[s][t][j];
          int col = t * 16 + fr;
          if constexpr (std::is_same<CT, float>::value)
            C[(size_t)row * 128 + col] = v;
          else
            ((ushort*)C)[(size_t)row * 128 + col] = f2bf(v);
        }
      }
    }
  }
}

// ---------------- attention scalars: a_src/a_dst [N,4] (xp is bf16) ----------------

__global__ __launch_bounds__(256) void k_att(const ushort* __restrict__ xp,
                                             const float* __restrict__ att_src,
                                             const float* __restrict__ att_dst,
                                             float* __restrict__ a_src,
                                             float* __restrict__ a_dst, int N) {
  int tid = threadIdx.x;
  int n = blockIdx.x * 2 + (tid >> 7);
  int c = tid & 127;
  int h = c >> 5, cc = c & 31;
  if (n >= N) return;
  float v = bf2f(xp[(size_t)n * 128 + c]);
  float vs = v * att_src[h * 32 + cc];
  float vd = v * att_dst[h * 32 + cc];
#pragma unroll
  for (int off = 16; off >= 1; off >>= 1) {
    vs += __shfl_xor(vs, off);
    vd += __shfl_xor(vd, off);
  }
  if (cc == 0) {
    a_src[n * 4 + h] = vs;
    a_dst[n * 4 + h] = vd;
  }
}

// ---------------- per-position logits (leaky-relu applied) ----------------

__global__ void k_edge(const int* __restrict__ ss, const int* __restrict__ ds,
                       const float* __restrict__ a_src, const float* __restrict__ a_dst,
                       float* __restrict__ e_sorted, int E) {
  int p = blockIdx.x * 256 + threadIdx.x;
  if (p >= E) return;
  int s = ss[p], d = ds[p];
  float4 as4 = *(const float4*)&a_src[s * 4];
  float4 ad4 = *(const float4*)&a_dst[d * 4];
  float4 ev;
  ev.x = as4.x + ad4.x; ev.x = (ev.x > 0.f) ? ev.x : SLOPE * ev.x;
  ev.y = as4.y + ad4.y; ev.y = (ev.y > 0.f) ? ev.y : SLOPE * ev.y;
  ev.z = as4.z + ad4.z; ev.z = (ev.z > 0.f) ? ev.z : SLOPE * ev.z;
  ev.w = as4.w + ad4.w; ev.w = (ev.w > 0.f) ? ev.w : SLOPE * ev.w;
  *(float4*)&e_sorted[p * 4] = ev;
}

// ---------------- per-node softmax + aggregation (bf16 gathers) ----------------

template <bool RELU, typename OT>
__global__ __launch_bounds__(128) void k_agg(const ushort* __restrict__ xp,
                                             const float* __restrict__ e_sorted,
                                             const int* __restrict__ src_sorted,
                                             const int* __restrict__ indptr,
                                             const int* __restrict__ counts,
                                             const float* __restrict__ bias,
                                             OT* __restrict__ out, int N) {
  int n = blockIdx.x;
  int c = threadIdx.x;
  int h = c >> 5;
  int deg = counts[n];
  int start = indptr[n];
  const float* eb = e_sorted + (size_t)start * 4 + h;
  const int* sp = src_sorted + start;

  float m0 = -INFINITY, m1 = -INFINITY, m2 = -INFINITY, m3 = -INFINITY;
  int i = 0;
  for (; i + 4 <= deg; i += 4) {
    float a = eb[(i + 0) * 4], b = eb[(i + 1) * 4];
    float d = eb[(i + 2) * 4], e = eb[(i + 3) * 4];
    m0 = fmaxf(m0, a); m1 = fmaxf(m1, b); m2 = fmaxf(m2, d); m3 = fmaxf(m3, e);
  }
  for (; i < deg; i++) m0 = fmaxf(m0, eb[i * 4]);
  float m = fmaxf(fmaxf(m0, m1), fmaxf(m2, m3));

  float s = 0.f, acc = 0.f;
  i = 0;
  for (; i + 4 <= deg; i += 4) {
    int s0 = sp[i], s1 = sp[i + 1], s2 = sp[i + 2], s3 = sp[i + 3];
    float e0 = eb[(i + 0) * 4], e1 = eb[(i + 1) * 4];
    float e2 = eb[(i + 2) * 4], e3 = eb[(i + 3) * 4];
    float v0 = bf2f(xp[(size_t)s0 * 128 + c]);
    float v1 = bf2f(xp[(size_t)s1 * 128 + c]);
    float v2 = bf2f(xp[(size_t)s2 * 128 + c]);
    float v3 = bf2f(xp[(size_t)s3 * 128 + c]);
    float x0 = __expf(e0 - m), x1 = __expf(e1 - m);
    float x2 = __expf(e2 - m), x3 = __expf(e3 - m);
    s += x0 + x1 + x2 + x3;
    acc = fmaf(v0, x0, acc); acc = fmaf(v1, x1, acc);
    acc = fmaf(v2, x2, acc); acc = fmaf(v3, x3, acc);
  }
  for (; i < deg; i++) {
    int s0 = sp[i];
    float x0 = __expf(eb[i * 4] - m);
    s += x0;
    acc = fmaf(bf2f(xp[(size_t)s0 * 128 + c]), x0, acc);
  }

  float inv = 1.f / (s + 1e-16f);
  float o = acc * inv + bias[c];
  if (RELU) o = fmaxf(o, 0.f);
  if constexpr (std::is_same<OT, float>::value)
    out[(size_t)n * 128 + c] = o;
  else
    ((ushort*)out)[(size_t)n * 128 + c] = f2bf(o);
}

// ---------------- launch ----------------

extern "C" void kernel_launch(void* const* d_in, const int* in_sizes, int n_in,
                              void* d_out, int out_size, void* d_ws, size_t ws_size,
                              hipStream_t stream) {
  const float* x   = (const float*)d_in[0];
  const int*   ei  = (const int*)d_in[1];
  const float* W0  = (const float*)d_in[2];
  const float* as0 = (const float*)d_in[3];
  const float* ad0 = (const float*)d_in[4];
  const float* b0  = (const float*)d_in[5];
  const float* W1  = (const float*)d_in[6];
  const float* as1 = (const float*)d_in[7];
  const float* ad1 = (const float*)d_in[8];
  const float* b1  = (const float*)d_in[9];

  const int N = in_sizes[0] / 256;   // 100000
  const int E = in_sizes[1] / 2;     // 800000
  const int* src = ei;
  const int* dst = ei + E;

  char* ws = (char*)d_ws;
  size_t off = 0;
  auto alloc = [&](size_t bytes) -> void* {
    void* p = ws + off;
    off += (bytes + 255) & ~(size_t)255;
    return p;
  };
  ushort* xp    = (ushort*)alloc((size_t)N * 128 * 2);
  ushort* hbuf  = (ushort*)alloc((size_t)N * 128 * 2);
  float* a_src  = (float*)alloc((size_t)N * 4 * 4);
  float* a_dst  = (float*)alloc((size_t)N * 4 * 4);
  float* e_sort = (float*)alloc((size_t)E * 4 * 4);
  int*   counts = (int*)alloc((size_t)N * 4);
  int*   indptr = (int*)alloc((size_t)N * 4);
  int*   cursor = (int*)alloc((size_t)N * 4);
  int*   ssort  = (int*)alloc((size_t)E * 4);
  int*   dsort  = (int*)alloc((size_t)E * 4);
  int*   bsums  = (int*)alloc(256 * 4);

  // ---- CSR build (by dst) ----
  hipMemsetAsync(counts, 0, (size_t)N * 4, stream);
  int eb = (E + 255) / 256;
  int nb = (N + 2047) / 2048;
  k_count<<<eb, 256, 0, stream>>>(dst, counts, E);
  k_scan1<<<nb, 256, 0, stream>>>(counts, indptr, bsums, N);
  k_scan2<<<1, 256, 0, stream>>>(bsums, nb);
  k_scan3<<<nb, 256, 0, stream>>>(indptr, cursor, bsums, N);
  k_fill<<<eb, 256, 0, stream>>>(src, dst, cursor, ssort, dsort, E);

  int gb = (N + 127) / 128;
  int ab = (N + 1) / 2;

  // ---- layer 0 ----
  k_gemm_mfma<float, ushort><<<gb, 256, 0, stream>>>(x, W0, xp, N, 256);
  k_att<<<ab, 256, 0, stream>>>(xp, as0, ad0, a_src, a_dst, N);
  k_edge<<<eb, 256, 0, stream>>>(ssort, dsort, a_src, a_dst, e_sort, E);
  k_agg<true, ushort><<<N, 128, 0, stream>>>(xp, e_sort, ssort, indptr, counts, b0, hbuf, N);

  // ---- layer 1 ----
  k_gemm_mfma<ushort, ushort><<<gb, 256, 0, stream>>>(hbuf, W1, xp, N, 128);
  k_att<<<ab, 256, 0, stream>>>(xp, as1, ad1, a_src, a_dst, N);
  k_edge<<<eb, 256, 0, stream>>>(ssort, dsort, a_src, a_dst, e_sort, E);
  k_agg<false, float><<<N, 128, 0, stream>>>(xp, e_sort, ssort, indptr, counts, b1,
                                             (float*)d_out, N);
}

// Round 4
// 317.993 us; speedup vs baseline: 3.4331x; 1.2567x over previous
//
#include <hip/hip_runtime.h>
#include <hip/hip_bf16.h>
#include <cstdint>
#include <cstddef>
#include <type_traits>

#define SLOPE 0.2f

typedef __attribute__((ext_vector_type(8))) short short8v;
typedef __attribute__((ext_vector_type(4))) float float4v;

__device__ inline ushort f2bf(float f) {
  uint u = __float_as_uint(f);
  uint r = (u + 0x7FFFu + ((u >> 16) & 1u)) >> 16;
  return (ushort)r;
}
__device__ inline float bf2f(ushort u) {
  return __uint_as_float(((uint)u) << 16);
}
__device__ inline float bflo(uint u) { return __uint_as_float(u << 16); }
__device__ inline float bfhi(uint u) { return __uint_as_float(u & 0xffff0000u); }

// ---------------- CSR build ----------------

__global__ void k_count(const int* __restrict__ dst, int* __restrict__ counts, int E) {
  int e = blockIdx.x * 256 + threadIdx.x;
  if (e < E) atomicAdd(&counts[dst[e]], 1);
}

__global__ void k_scan1(const int* __restrict__ counts, int* __restrict__ excl,
                        int* __restrict__ bsums, int N) {
  __shared__ int lds[256];
  int tid = threadIdx.x;
  int base = blockIdx.x * 2048 + tid * 8;
  int v[8];
  int ts = 0;
#pragma unroll
  for (int i = 0; i < 8; i++) {
    int idx = base + i;
    int t = (idx < N) ? counts[idx] : 0;
    v[i] = ts;
    ts += t;
  }
  lds[tid] = ts;
  __syncthreads();
  for (int off = 1; off < 256; off <<= 1) {
    int t = (tid >= off) ? lds[tid - off] : 0;
    __syncthreads();
    lds[tid] += t;
    __syncthreads();
  }
  int texcl = (tid > 0) ? lds[tid - 1] : 0;
#pragma unroll
  for (int i = 0; i < 8; i++) {
    int idx = base + i;
    if (idx < N) excl[idx] = texcl + v[i];
  }
  if (tid == 255) bsums[blockIdx.x] = lds[255];
}

__global__ void k_scan2(int* bsums, int nb) {
  __shared__ int lds[256];
  int tid = threadIdx.x;
  int v = (tid < nb) ? bsums[tid] : 0;
  lds[tid] = v;
  __syncthreads();
  for (int off = 1; off < 256; off <<= 1) {
    int t = (tid >= off) ? lds[tid - off] : 0;
    __syncthreads();
    lds[tid] += t;
    __syncthreads();
  }
  if (tid < nb) bsums[tid] = (tid > 0) ? lds[tid - 1] : 0;
}

__global__ void k_scan3(int* __restrict__ excl, int* __restrict__ cursor,
                        const int* __restrict__ bsums, int N) {
  int tid = threadIdx.x;
  int off = bsums[blockIdx.x];
  int base = blockIdx.x * 2048 + tid * 8;
#pragma unroll
  for (int i = 0; i < 8; i++) {
    int idx = base + i;
    if (idx < N) {
      int val = excl[idx] + off;
      excl[idx] = val;
      cursor[idx] = val;
    }
  }
}

__global__ void k_fill(const int* __restrict__ src, const int* __restrict__ dst,
                       int* __restrict__ cursor,
                       int* __restrict__ src_sorted, int* __restrict__ dst_sorted,
                       int E) {
  int e = blockIdx.x * 256 + threadIdx.x;
  if (e < E) {
    int d = dst[e];
    int pos = atomicAdd(&cursor[d], 1);
    src_sorted[pos] = src[e];
    dst_sorted[pos] = d;
  }
}

// ---------------- MFMA GEMM: C[M,128] = A[M,K] @ W[128,K]^T ----------------

template <typename AT, typename CT>
__global__ __launch_bounds__(256) void k_gemm_mfma(const AT* __restrict__ A,
                                                   const float* __restrict__ W,
                                                   CT* __restrict__ C,
                                                   int M, int K) {
  __shared__ ushort As[128 * 40];
  __shared__ ushort Ws[128 * 40];
  const int tid = threadIdx.x;
  const int wave = tid >> 6, lane = tid & 63;
  const int bm = blockIdx.x * 128;
  const int r = tid >> 1;            // staging row 0..127
  const int cb = (tid & 1) * 16;     // staging col base {0,16}
  const int fr = lane & 15, fq = lane >> 4;
  float4v acc[2][8] = {};

  for (int k0 = 0; k0 < K; k0 += 32) {
    const bool valid = (bm + r) < M;
    if constexpr (std::is_same<AT, float>::value) {
      const float* ap = A + (size_t)(bm + r) * K + k0 + cb;
#pragma unroll
      for (int i = 0; i < 4; i++) {
        float4 v = valid ? *(const float4*)(ap + i * 4) : make_float4(0.f, 0.f, 0.f, 0.f);
        ushort4 pk;
        pk.x = f2bf(v.x); pk.y = f2bf(v.y); pk.z = f2bf(v.z); pk.w = f2bf(v.w);
        *(ushort4*)&As[r * 40 + cb + i * 4] = pk;
      }
    } else {
      const ushort* ap = (const ushort*)A + (size_t)(bm + r) * K + k0 + cb;
#pragma unroll
      for (int i = 0; i < 2; i++) {
        uint4 v = valid ? *(const uint4*)(ap + i * 8) : make_uint4(0, 0, 0, 0);
        *(uint4*)&As[r * 40 + cb + i * 8] = v;
      }
    }
    {
      const float* wp = W + (size_t)r * K + k0 + cb;
#pragma unroll
      for (int i = 0; i < 4; i++) {
        float4 v = *(const float4*)(wp + i * 4);
        ushort4 pk;
        pk.x = f2bf(v.x); pk.y = f2bf(v.y); pk.z = f2bf(v.z); pk.w = f2bf(v.w);
        *(ushort4*)&Ws[r * 40 + cb + i * 4] = pk;
      }
    }
    __syncthreads();
    short8v af[2];
    short8v bfr[8];
#pragma unroll
    for (int s = 0; s < 2; s++)
      af[s] = *(const short8v*)&As[(wave * 32 + s * 16 + fr) * 40 + fq * 8];
#pragma unroll
    for (int t = 0; t < 8; t++)
      bfr[t] = *(const short8v*)&Ws[(t * 16 + fr) * 40 + fq * 8];
#pragma unroll
    for (int s = 0; s < 2; s++)
#pragma unroll
      for (int t = 0; t < 8; t++)
        acc[s][t] = __builtin_amdgcn_mfma_f32_16x16x32_bf16(af[s], bfr[t], acc[s][t], 0, 0, 0);
    __syncthreads();
  }

#pragma unroll
  for (int s = 0; s < 2; s++) {
#pragma unroll
    for (int j = 0; j < 4; j++) {
      int row = bm + wave * 32 + s * 16 + fq * 4 + j;
      if (row < M) {
#pragma unroll
        for (int t = 0; t < 8; t++) {
          float v = acc[s][t][j];
          int col = t * 16 + fr;
          if constexpr (std::is_same<CT, float>::value)
            C[(size_t)row * 128 + col] = v;
          else
            ((ushort*)C)[(size_t)row * 128 + col] = f2bf(v);
        }
      }
    }
  }
}

// ---------------- attention scalars: a_src/a_dst [N,4] (xp is bf16) ----------------

__global__ __launch_bounds__(256) void k_att(const ushort* __restrict__ xp,
                                             const float* __restrict__ att_src,
                                             const float* __restrict__ att_dst,
                                             float* __restrict__ a_src,
                                             float* __restrict__ a_dst, int N) {
  int tid = threadIdx.x;
  int n = blockIdx.x * 2 + (tid >> 7);
  int c = tid & 127;
  int h = c >> 5, cc = c & 31;
  if (n >= N) return;
  float v = bf2f(xp[(size_t)n * 128 + c]);
  float vs = v * att_src[h * 32 + cc];
  float vd = v * att_dst[h * 32 + cc];
#pragma unroll
  for (int off = 16; off >= 1; off >>= 1) {
    vs += __shfl_xor(vs, off);
    vd += __shfl_xor(vd, off);
  }
  if (cc == 0) {
    a_src[n * 4 + h] = vs;
    a_dst[n * 4 + h] = vd;
  }
}

// ---------------- per-position logits (leaky-relu applied) ----------------

__global__ void k_edge(const int* __restrict__ ss, const int* __restrict__ ds,
                       const float* __restrict__ a_src, const float* __restrict__ a_dst,
                       float* __restrict__ e_sorted, int E) {
  int p = blockIdx.x * 256 + threadIdx.x;
  if (p >= E) return;
  int s = ss[p], d = ds[p];
  float4 as4 = *(const float4*)&a_src[s * 4];
  float4 ad4 = *(const float4*)&a_dst[d * 4];
  float4 ev;
  ev.x = as4.x + ad4.x; ev.x = (ev.x > 0.f) ? ev.x : SLOPE * ev.x;
  ev.y = as4.y + ad4.y; ev.y = (ev.y > 0.f) ? ev.y : SLOPE * ev.y;
  ev.z = as4.z + ad4.z; ev.z = (ev.z > 0.f) ? ev.z : SLOPE * ev.z;
  ev.w = as4.w + ad4.w; ev.w = (ev.w > 0.f) ? ev.w : SLOPE * ev.w;
  *(float4*)&e_sorted[p * 4] = ev;
}

// ---------------- per-(node,head) softmax stats: m, 1/(s+eps) ----------------

__global__ __launch_bounds__(256) void k_msum(const float* __restrict__ e_sorted,
                                              const int* __restrict__ indptr,
                                              const int* __restrict__ counts,
                                              float* __restrict__ m_buf,
                                              float* __restrict__ inv_buf, int N) {
  int t = blockIdx.x * 256 + threadIdx.x;
  int n = t >> 2, h = t & 3;
  if (n >= N) return;
  int deg = counts[n], start = indptr[n];
  const float* eb = e_sorted + (size_t)start * 4 + h;
  float m0 = -INFINITY, m1 = -INFINITY, m2 = -INFINITY, m3 = -INFINITY;
  int i = 0;
  for (; i + 4 <= deg; i += 4) {
    float a = eb[(i + 0) * 4], b = eb[(i + 1) * 4];
    float c = eb[(i + 2) * 4], d = eb[(i + 3) * 4];
    m0 = fmaxf(m0, a); m1 = fmaxf(m1, b); m2 = fmaxf(m2, c); m3 = fmaxf(m3, d);
  }
  for (; i < deg; i++) m0 = fmaxf(m0, eb[i * 4]);
  float m = fmaxf(fmaxf(m0, m1), fmaxf(m2, m3));
  float s = 0.f;
  i = 0;
  for (; i + 4 <= deg; i += 4) {
    float a = eb[(i + 0) * 4], b = eb[(i + 1) * 4];
    float c = eb[(i + 2) * 4], d = eb[(i + 3) * 4];
    s += __expf(a - m) + __expf(b - m) + __expf(c - m) + __expf(d - m);
  }
  for (; i < deg; i++) s += __expf(eb[i * 4] - m);
  m_buf[t] = m;
  inv_buf[t] = 1.f / (s + 1e-16f);
}

// ---------------- aggregation: 32 threads/node, 4 channels/thread ----------------

template <bool RELU, typename OT>
__global__ __launch_bounds__(256) void k_agg(const ushort* __restrict__ xp,
                                             const float* __restrict__ e_sorted,
                                             const int* __restrict__ src_sorted,
                                             const int* __restrict__ indptr,
                                             const int* __restrict__ counts,
                                             const float* __restrict__ m_buf,
                                             const float* __restrict__ inv_buf,
                                             const float* __restrict__ bias,
                                             OT* __restrict__ out, int N) {
  int tid = threadIdx.x;
  int n = blockIdx.x * 8 + (tid >> 5);
  if (n >= N) return;
  int c4 = tid & 31;          // channel group: channels 4*c4 .. 4*c4+3
  int h = c4 >> 3;
  int deg = counts[n];
  int start = indptr[n];
  const float* eb = e_sorted + (size_t)start * 4 + h;
  const int* sp = src_sorted + start;
  const ushort* xpc = xp + c4 * 4;
  float m = m_buf[n * 4 + h];
  float inv = inv_buf[n * 4 + h];

  float a0 = 0.f, a1 = 0.f, a2 = 0.f, a3 = 0.f;
  int i = 0;
  for (; i + 4 <= deg; i += 4) {
    int s0 = sp[i], s1 = sp[i + 1], s2 = sp[i + 2], s3 = sp[i + 3];
    float e0 = eb[(i + 0) * 4], e1 = eb[(i + 1) * 4];
    float e2 = eb[(i + 2) * 4], e3 = eb[(i + 3) * 4];
    uint2 v0 = *(const uint2*)(xpc + (size_t)s0 * 128);
    uint2 v1 = *(const uint2*)(xpc + (size_t)s1 * 128);
    uint2 v2 = *(const uint2*)(xpc + (size_t)s2 * 128);
    uint2 v3 = *(const uint2*)(xpc + (size_t)s3 * 128);
    float x0 = __expf(e0 - m), x1 = __expf(e1 - m);
    float x2 = __expf(e2 - m), x3 = __expf(e3 - m);
    a0 = fmaf(bflo(v0.x), x0, a0); a1 = fmaf(bfhi(v0.x), x0, a1);
    a2 = fmaf(bflo(v0.y), x0, a2); a3 = fmaf(bfhi(v0.y), x0, a3);
    a0 = fmaf(bflo(v1.x), x1, a0); a1 = fmaf(bfhi(v1.x), x1, a1);
    a2 = fmaf(bflo(v1.y), x1, a2); a3 = fmaf(bfhi(v1.y), x1, a3);
    a0 = fmaf(bflo(v2.x), x2, a0); a1 = fmaf(bfhi(v2.x), x2, a1);
    a2 = fmaf(bflo(v2.y), x2, a2); a3 = fmaf(bfhi(v2.y), x2, a3);
    a0 = fmaf(bflo(v3.x), x3, a0); a1 = fmaf(bfhi(v3.x), x3, a1);
    a2 = fmaf(bflo(v3.y), x3, a2); a3 = fmaf(bfhi(v3.y), x3, a3);
  }
  for (; i < deg; i++) {
    int s0 = sp[i];
    float x0 = __expf(eb[i * 4] - m);
    uint2 v0 = *(const uint2*)(xpc + (size_t)s0 * 128);
    a0 = fmaf(bflo(v0.x), x0, a0); a1 = fmaf(bfhi(v0.x), x0, a1);
    a2 = fmaf(bflo(v0.y), x0, a2); a3 = fmaf(bfhi(v0.y), x0, a3);
  }

  float4 bv = *(const float4*)&bias[c4 * 4];
  float o0 = fmaf(a0, inv, bv.x);
  float o1 = fmaf(a1, inv, bv.y);
  float o2 = fmaf(a2, inv, bv.z);
  float o3 = fmaf(a3, inv, bv.w);
  if (RELU) {
    o0 = fmaxf(o0, 0.f); o1 = fmaxf(o1, 0.f);
    o2 = fmaxf(o2, 0.f); o3 = fmaxf(o3, 0.f);
  }
  if constexpr (std::is_same<OT, float>::value) {
    *(float4*)&out[(size_t)n * 128 + c4 * 4] = make_float4(o0, o1, o2, o3);
  } else {
    uint2 pk;
    pk.x = (uint)f2bf(o0) | ((uint)f2bf(o1) << 16);
    pk.y = (uint)f2bf(o2) | ((uint)f2bf(o3) << 16);
    *(uint2*)&((ushort*)out)[(size_t)n * 128 + c4 * 4] = pk;
  }
}

// ---------------- launch ----------------

extern "C" void kernel_launch(void* const* d_in, const int* in_sizes, int n_in,
                              void* d_out, int out_size, void* d_ws, size_t ws_size,
                              hipStream_t stream) {
  const float* x   = (const float*)d_in[0];
  const int*   ei  = (const int*)d_in[1];
  const float* W0  = (const float*)d_in[2];
  const float* as0 = (const float*)d_in[3];
  const float* ad0 = (const float*)d_in[4];
  const float* b0  = (const float*)d_in[5];
  const float* W1  = (const float*)d_in[6];
  const float* as1 = (const float*)d_in[7];
  const float* ad1 = (const float*)d_in[8];
  const float* b1  = (const float*)d_in[9];

  const int N = in_sizes[0] / 256;   // 100000
  const int E = in_sizes[1] / 2;     // 800000
  const int* src = ei;
  const int* dst = ei + E;

  char* ws = (char*)d_ws;
  size_t off = 0;
  auto alloc = [&](size_t bytes) -> void* {
    void* p = ws + off;
    off += (bytes + 255) & ~(size_t)255;
    return p;
  };
  ushort* xp    = (ushort*)alloc((size_t)N * 128 * 2);
  ushort* hbuf  = (ushort*)alloc((size_t)N * 128 * 2);
  float* a_src  = (float*)alloc((size_t)N * 4 * 4);
  float* a_dst  = (float*)alloc((size_t)N * 4 * 4);
  float* e_sort = (float*)alloc((size_t)E * 4 * 4);
  float* m_buf  = (float*)alloc((size_t)N * 4 * 4);
  float* i_buf  = (float*)alloc((size_t)N * 4 * 4);
  int*   counts = (int*)alloc((size_t)N * 4);
  int*   indptr = (int*)alloc((size_t)N * 4);
  int*   cursor = (int*)alloc((size_t)N * 4);
  int*   ssort  = (int*)alloc((size_t)E * 4);
  int*   dsort  = (int*)alloc((size_t)E * 4);
  int*   bsums  = (int*)alloc(256 * 4);

  // ---- CSR build (by dst) ----
  hipMemsetAsync(counts, 0, (size_t)N * 4, stream);
  int eb = (E + 255) / 256;
  int nb = (N + 2047) / 2048;
  k_count<<<eb, 256, 0, stream>>>(dst, counts, E);
  k_scan1<<<nb, 256, 0, stream>>>(counts, indptr, bsums, N);
  k_scan2<<<1, 256, 0, stream>>>(bsums, nb);
  k_scan3<<<nb, 256, 0, stream>>>(indptr, cursor, bsums, N);
  k_fill<<<eb, 256, 0, stream>>>(src, dst, cursor, ssort, dsort, E);

  int gb = (N + 127) / 128;
  int ab = (N + 1) / 2;
  int mb = (N * 4 + 255) / 256;
  int gb8 = (N + 7) / 8;

  // ---- layer 0 ----
  k_gemm_mfma<float, ushort><<<gb, 256, 0, stream>>>(x, W0, xp, N, 256);
  k_att<<<ab, 256, 0, stream>>>(xp, as0, ad0, a_src, a_dst, N);
  k_edge<<<eb, 256, 0, stream>>>(ssort, dsort, a_src, a_dst, e_sort, E);
  k_msum<<<mb, 256, 0, stream>>>(e_sort, indptr, counts, m_buf, i_buf, N);
  k_agg<true, ushort><<<gb8, 256, 0, stream>>>(xp, e_sort, ssort, indptr, counts,
                                               m_buf, i_buf, b0, hbuf, N);

  // ---- layer 1 ----
  k_gemm_mfma<ushort, ushort><<<gb, 256, 0, stream>>>(hbuf, W1, xp, N, 128);
  k_att<<<ab, 256, 0, stream>>>(xp, as1, ad1, a_src, a_dst, N);
  k_edge<<<eb, 256, 0, stream>>>(ssort, dsort, a_src, a_dst, e_sort, E);
  k_msum<<<mb, 256, 0, stream>>>(e_sort, indptr, counts, m_buf, i_buf, N);
  k_agg<false, float><<<gb8, 256, 0, stream>>>(xp, e_sort, ssort, indptr, counts,
                                               m_buf, i_buf, b1, (float*)d_out, N);
}

// Round 5
// 297.376 us; speedup vs baseline: 3.6711x; 1.0693x over previous
//
#include <hip/hip_runtime.h>
#include <hip/hip_bf16.h>
#include <cstdint>
#include <cstddef>
#include <type_traits>

#define SLOPE 0.2f

typedef __attribute__((ext_vector_type(8))) short short8v;
typedef __attribute__((ext_vector_type(4))) float float4v;

__device__ inline ushort f2bf(float f) {
  uint u = __float_as_uint(f);
  uint r = (u + 0x7FFFu + ((u >> 16) & 1u)) >> 16;
  return (ushort)r;
}
__device__ inline float bf2f(ushort u) {
  return __uint_as_float(((uint)u) << 16);
}
__device__ inline float bflo(uint u) { return __uint_as_float(u << 16); }
__device__ inline float bfhi(uint u) { return __uint_as_float(u & 0xffff0000u); }

__device__ inline short8v pack8(float4 a, float4 b) {
  uint4 r;
  r.x = (uint)f2bf(a.x) | ((uint)f2bf(a.y) << 16);
  r.y = (uint)f2bf(a.z) | ((uint)f2bf(a.w) << 16);
  r.z = (uint)f2bf(b.x) | ((uint)f2bf(b.y) << 16);
  r.w = (uint)f2bf(b.z) | ((uint)f2bf(b.w) << 16);
  return __builtin_bit_cast(short8v, r);
}

// ---------------- W pre-conversion (once) ----------------

__global__ void k_wconv(const float* __restrict__ W0, const float* __restrict__ W1,
                        ushort* __restrict__ Wb0, ushort* __restrict__ Wb1) {
  int i = blockIdx.x * 256 + threadIdx.x;
  if (i < 128 * 256) Wb0[i] = f2bf(W0[i]);
  if (i < 128 * 128) Wb1[i] = f2bf(W1[i]);
}

// ---------------- CSR build ----------------

__global__ void k_count(const int* __restrict__ dst, int* __restrict__ counts, int E) {
  int e = blockIdx.x * 256 + threadIdx.x;
  if (e < E) atomicAdd(&counts[dst[e]], 1);
}

__global__ void k_scan1(const int* __restrict__ counts, int* __restrict__ excl,
                        int* __restrict__ bsums, int N) {
  __shared__ int lds[256];
  int tid = threadIdx.x;
  int base = blockIdx.x * 2048 + tid * 8;
  int v[8];
  int ts = 0;
#pragma unroll
  for (int i = 0; i < 8; i++) {
    int idx = base + i;
    int t = (idx < N) ? counts[idx] : 0;
    v[i] = ts;
    ts += t;
  }
  lds[tid] = ts;
  __syncthreads();
  for (int off = 1; off < 256; off <<= 1) {
    int t = (tid >= off) ? lds[tid - off] : 0;
    __syncthreads();
    lds[tid] += t;
    __syncthreads();
  }
  int texcl = (tid > 0) ? lds[tid - 1] : 0;
#pragma unroll
  for (int i = 0; i < 8; i++) {
    int idx = base + i;
    if (idx < N) excl[idx] = texcl + v[i];
  }
  if (tid == 255) bsums[blockIdx.x] = lds[255];
}

__global__ void k_scan2(int* bsums, int nb) {
  __shared__ int lds[256];
  int tid = threadIdx.x;
  int v = (tid < nb) ? bsums[tid] : 0;
  lds[tid] = v;
  __syncthreads();
  for (int off = 1; off < 256; off <<= 1) {
    int t = (tid >= off) ? lds[tid - off] : 0;
    __syncthreads();
    lds[tid] += t;
    __syncthreads();
  }
  if (tid < nb) bsums[tid] = (tid > 0) ? lds[tid - 1] : 0;
}

__global__ void k_scan3(int* __restrict__ excl, int* __restrict__ cursor,
                        const int* __restrict__ bsums, int N) {
  int tid = threadIdx.x;
  int off = bsums[blockIdx.x];
  int base = blockIdx.x * 2048 + tid * 8;
#pragma unroll
  for (int i = 0; i < 8; i++) {
    int idx = base + i;
    if (idx < N) {
      int val = excl[idx] + off;
      excl[idx] = val;
      cursor[idx] = val;
    }
  }
}

__global__ void k_fill(const int* __restrict__ src, const int* __restrict__ dst,
                       int* __restrict__ cursor,
                       int* __restrict__ src_sorted, int* __restrict__ dst_sorted,
                       int E) {
  int e = blockIdx.x * 256 + threadIdx.x;
  if (e < E) {
    int d = dst[e];
    int pos = atomicAdd(&cursor[d], 1);
    src_sorted[pos] = src[e];
    dst_sorted[pos] = d;
  }
}

// ---------------- direct-to-register MFMA GEMM + fused attention scalars ----
// C[M,128] = A[M,K] @ Wb[128,K]^T   (Wb pre-converted bf16)
// No LDS, no barriers: A and W fragments loaded straight to registers.
// Epilogue computes a_src/a_dst (att reductions) from fp32 accumulators.

template <typename AT, int K>
__global__ __launch_bounds__(256, 2) void k_gemm_direct(
    const AT* __restrict__ A, const ushort* __restrict__ Wb,
    const float* __restrict__ att_src, const float* __restrict__ att_dst,
    ushort* __restrict__ C, float* __restrict__ a_src, float* __restrict__ a_dst,
    int M) {
  const int tid = threadIdx.x;
  const int wave = tid >> 6, lane = tid & 63;
  const int fr = lane & 15, fq = lane >> 4;
  const int bm = blockIdx.x * 128;
  const int r0 = bm + wave * 32 + fr;
  const int r1 = r0 + 16;
  const int rc0 = min(r0, M - 1), rc1 = min(r1, M - 1);
  float4v acc[2][8] = {};

#pragma unroll
  for (int k0 = 0; k0 < K; k0 += 32) {
    short8v bfr[8];
#pragma unroll
    for (int t = 0; t < 8; t++)
      bfr[t] = *(const short8v*)(Wb + (size_t)(t * 16 + fr) * K + k0 + fq * 8);
    short8v af0, af1;
    if constexpr (std::is_same<AT, float>::value) {
      const float* p0 = A + (size_t)rc0 * K + k0 + fq * 8;
      const float* p1 = A + (size_t)rc1 * K + k0 + fq * 8;
      af0 = pack8(*(const float4*)p0, *(const float4*)(p0 + 4));
      af1 = pack8(*(const float4*)p1, *(const float4*)(p1 + 4));
    } else {
      af0 = *(const short8v*)(A + (size_t)rc0 * K + k0 + fq * 8);
      af1 = *(const short8v*)(A + (size_t)rc1 * K + k0 + fq * 8);
    }
#pragma unroll
    for (int t = 0; t < 8; t++)
      acc[0][t] = __builtin_amdgcn_mfma_f32_16x16x32_bf16(af0, bfr[t], acc[0][t], 0, 0, 0);
#pragma unroll
    for (int t = 0; t < 8; t++)
      acc[1][t] = __builtin_amdgcn_mfma_f32_16x16x32_bf16(af1, bfr[t], acc[1][t], 0, 0, 0);
  }

  // att coefficients for this lane's columns (t*16+fr)
  float asc[8], adc[8];
#pragma unroll
  for (int t = 0; t < 8; t++) {
    asc[t] = att_src[t * 16 + fr];
    adc[t] = att_dst[t * 16 + fr];
  }

#pragma unroll
  for (int s = 0; s < 2; s++) {
#pragma unroll
    for (int j = 0; j < 4; j++) {
      int row = bm + wave * 32 + s * 16 + fq * 4 + j;
      bool ok = row < M;
      // C store (8 scalar bf16, coalesced across the 16-lane fr group)
      if (ok) {
#pragma unroll
        for (int t = 0; t < 8; t++)
          C[(size_t)row * 128 + t * 16 + fr] = f2bf(acc[s][t][j]);
      }
      // fused a_src/a_dst: per-head partial over this lane's 8 columns
      float ps[4], pd[4];
#pragma unroll
      for (int h = 0; h < 4; h++) {
        ps[h] = acc[s][2 * h][j] * asc[2 * h] + acc[s][2 * h + 1][j] * asc[2 * h + 1];
        pd[h] = acc[s][2 * h][j] * adc[2 * h] + acc[s][2 * h + 1][j] * adc[2 * h + 1];
      }
#pragma unroll
      for (int off = 1; off < 16; off <<= 1) {
#pragma unroll
        for (int h = 0; h < 4; h++) {
          ps[h] += __shfl_xor(ps[h], off);
          pd[h] += __shfl_xor(pd[h], off);
        }
      }
      if (ok && fr == 0) {
        *(float4*)&a_src[(size_t)row * 4] = make_float4(ps[0], ps[1], ps[2], ps[3]);
        *(float4*)&a_dst[(size_t)row * 4] = make_float4(pd[0], pd[1], pd[2], pd[3]);
      }
    }
  }
}

// ---------------- per-position logits (leaky-relu applied) ----------------

__global__ void k_edge(const int* __restrict__ ss, const int* __restrict__ ds,
                       const float* __restrict__ a_src, const float* __restrict__ a_dst,
                       float* __restrict__ e_sorted, int E) {
  int p = blockIdx.x * 256 + threadIdx.x;
  if (p >= E) return;
  int s = ss[p], d = ds[p];
  float4 as4 = *(const float4*)&a_src[s * 4];
  float4 ad4 = *(const float4*)&a_dst[d * 4];
  float4 ev;
  ev.x = as4.x + ad4.x; ev.x = (ev.x > 0.f) ? ev.x : SLOPE * ev.x;
  ev.y = as4.y + ad4.y; ev.y = (ev.y > 0.f) ? ev.y : SLOPE * ev.y;
  ev.z = as4.z + ad4.z; ev.z = (ev.z > 0.f) ? ev.z : SLOPE * ev.z;
  ev.w = as4.w + ad4.w; ev.w = (ev.w > 0.f) ? ev.w : SLOPE * ev.w;
  *(float4*)&e_sorted[p * 4] = ev;
}

// ---------------- per-(node,head) softmax stats: m, 1/(s+eps) ----------------

__global__ __launch_bounds__(256) void k_msum(const float* __restrict__ e_sorted,
                                              const int* __restrict__ indptr,
                                              const int* __restrict__ counts,
                                              float* __restrict__ m_buf,
                                              float* __restrict__ inv_buf, int N) {
  int t = blockIdx.x * 256 + threadIdx.x;
  int n = t >> 2, h = t & 3;
  if (n >= N) return;
  int deg = counts[n], start = indptr[n];
  const float* eb = e_sorted + (size_t)start * 4 + h;
  float m0 = -INFINITY, m1 = -INFINITY, m2 = -INFINITY, m3 = -INFINITY;
  int i = 0;
  for (; i + 4 <= deg; i += 4) {
    float a = eb[(i + 0) * 4], b = eb[(i + 1) * 4];
    float c = eb[(i + 2) * 4], d = eb[(i + 3) * 4];
    m0 = fmaxf(m0, a); m1 = fmaxf(m1, b); m2 = fmaxf(m2, c); m3 = fmaxf(m3, d);
  }
  for (; i < deg; i++) m0 = fmaxf(m0, eb[i * 4]);
  float m = fmaxf(fmaxf(m0, m1), fmaxf(m2, m3));
  float s = 0.f;
  i = 0;
  for (; i + 4 <= deg; i += 4) {
    float a = eb[(i + 0) * 4], b = eb[(i + 1) * 4];
    float c = eb[(i + 2) * 4], d = eb[(i + 3) * 4];
    s += __expf(a - m) + __expf(b - m) + __expf(c - m) + __expf(d - m);
  }
  for (; i < deg; i++) s += __expf(eb[i * 4] - m);
  m_buf[t] = m;
  inv_buf[t] = 1.f / (s + 1e-16f);
}

// ---------------- aggregation: 32 threads/node, 4 channels/thread ----------------

template <bool RELU, typename OT>
__global__ __launch_bounds__(256) void k_agg(const ushort* __restrict__ xp,
                                             const float* __restrict__ e_sorted,
                                             const int* __restrict__ src_sorted,
                                             const int* __restrict__ indptr,
                                             const int* __restrict__ counts,
                                             const float* __restrict__ m_buf,
                                             const float* __restrict__ inv_buf,
                                             const float* __restrict__ bias,
                                             OT* __restrict__ out, int N) {
  int tid = threadIdx.x;
  int n = blockIdx.x * 8 + (tid >> 5);
  if (n >= N) return;
  int c4 = tid & 31;          // channel group: channels 4*c4 .. 4*c4+3
  int h = c4 >> 3;
  int deg = counts[n];
  int start = indptr[n];
  const float* eb = e_sorted + (size_t)start * 4 + h;
  const int* sp = src_sorted + start;
  const ushort* xpc = xp + c4 * 4;
  float m = m_buf[n * 4 + h];
  float inv = inv_buf[n * 4 + h];

  float a0 = 0.f, a1 = 0.f, a2 = 0.f, a3 = 0.f;
  int i = 0;
  for (; i + 4 <= deg; i += 4) {
    int s0 = sp[i], s1 = sp[i + 1], s2 = sp[i + 2], s3 = sp[i + 3];
    float e0 = eb[(i + 0) * 4], e1 = eb[(i + 1) * 4];
    float e2 = eb[(i + 2) * 4], e3 = eb[(i + 3) * 4];
    uint2 v0 = *(const uint2*)(xpc + (size_t)s0 * 128);
    uint2 v1 = *(const uint2*)(xpc + (size_t)s1 * 128);
    uint2 v2 = *(const uint2*)(xpc + (size_t)s2 * 128);
    uint2 v3 = *(const uint2*)(xpc + (size_t)s3 * 128);
    float x0 = __expf(e0 - m), x1 = __expf(e1 - m);
    float x2 = __expf(e2 - m), x3 = __expf(e3 - m);
    a0 = fmaf(bflo(v0.x), x0, a0); a1 = fmaf(bfhi(v0.x), x0, a1);
    a2 = fmaf(bflo(v0.y), x0, a2); a3 = fmaf(bfhi(v0.y), x0, a3);
    a0 = fmaf(bflo(v1.x), x1, a0); a1 = fmaf(bfhi(v1.x), x1, a1);
    a2 = fmaf(bflo(v1.y), x1, a2); a3 = fmaf(bfhi(v1.y), x1, a3);
    a0 = fmaf(bflo(v2.x), x2, a0); a1 = fmaf(bfhi(v2.x), x2, a1);
    a2 = fmaf(bflo(v2.y), x2, a2); a3 = fmaf(bfhi(v2.y), x2, a3);
    a0 = fmaf(bflo(v3.x), x3, a0); a1 = fmaf(bfhi(v3.x), x3, a1);
    a2 = fmaf(bflo(v3.y), x3, a2); a3 = fmaf(bfhi(v3.y), x3, a3);
  }
  for (; i < deg; i++) {
    int s0 = sp[i];
    float x0 = __expf(eb[i * 4] - m);
    uint2 v0 = *(const uint2*)(xpc + (size_t)s0 * 128);
    a0 = fmaf(bflo(v0.x), x0, a0); a1 = fmaf(bfhi(v0.x), x0, a1);
    a2 = fmaf(bflo(v0.y), x0, a2); a3 = fmaf(bfhi(v0.y), x0, a3);
  }

  float4 bv = *(const float4*)&bias[c4 * 4];
  float o0 = fmaf(a0, inv, bv.x);
  float o1 = fmaf(a1, inv, bv.y);
  float o2 = fmaf(a2, inv, bv.z);
  float o3 = fmaf(a3, inv, bv.w);
  if (RELU) {
    o0 = fmaxf(o0, 0.f); o1 = fmaxf(o1, 0.f);
    o2 = fmaxf(o2, 0.f); o3 = fmaxf(o3, 0.f);
  }
  if constexpr (std::is_same<OT, float>::value) {
    *(float4*)&out[(size_t)n * 128 + c4 * 4] = make_float4(o0, o1, o2, o3);
  } else {
    uint2 pk;
    pk.x = (uint)f2bf(o0) | ((uint)f2bf(o1) << 16);
    pk.y = (uint)f2bf(o2) | ((uint)f2bf(o3) << 16);
    *(uint2*)&((ushort*)out)[(size_t)n * 128 + c4 * 4] = pk;
  }
}

// ---------------- launch ----------------

extern "C" void kernel_launch(void* const* d_in, const int* in_sizes, int n_in,
                              void* d_out, int out_size, void* d_ws, size_t ws_size,
                              hipStream_t stream) {
  const float* x   = (const float*)d_in[0];
  const int*   ei  = (const int*)d_in[1];
  const float* W0  = (const float*)d_in[2];
  const float* as0 = (const float*)d_in[3];
  const float* ad0 = (const float*)d_in[4];
  const float* b0  = (const float*)d_in[5];
  const float* W1  = (const float*)d_in[6];
  const float* as1 = (const float*)d_in[7];
  const float* ad1 = (const float*)d_in[8];
  const float* b1  = (const float*)d_in[9];

  const int N = in_sizes[0] / 256;   // 100000
  const int E = in_sizes[1] / 2;     // 800000
  const int* src = ei;
  const int* dst = ei + E;

  char* ws = (char*)d_ws;
  size_t off = 0;
  auto alloc = [&](size_t bytes) -> void* {
    void* p = ws + off;
    off += (bytes + 255) & ~(size_t)255;
    return p;
  };
  ushort* xp    = (ushort*)alloc((size_t)N * 128 * 2);
  ushort* hbuf  = (ushort*)alloc((size_t)N * 128 * 2);
  float* a_src  = (float*)alloc((size_t)N * 4 * 4);
  float* a_dst  = (float*)alloc((size_t)N * 4 * 4);
  float* e_sort = (float*)alloc((size_t)E * 4 * 4);
  float* m_buf  = (float*)alloc((size_t)N * 4 * 4);
  float* i_buf  = (float*)alloc((size_t)N * 4 * 4);
  int*   counts = (int*)alloc((size_t)N * 4);
  int*   indptr = (int*)alloc((size_t)N * 4);
  int*   cursor = (int*)alloc((size_t)N * 4);
  int*   ssort  = (int*)alloc((size_t)E * 4);
  int*   dsort  = (int*)alloc((size_t)E * 4);
  int*   bsums  = (int*)alloc(256 * 4);
  ushort* Wb0   = (ushort*)alloc((size_t)128 * 256 * 2);
  ushort* Wb1   = (ushort*)alloc((size_t)128 * 128 * 2);

  // ---- W conversion + CSR build (by dst) ----
  hipMemsetAsync(counts, 0, (size_t)N * 4, stream);
  int eb = (E + 255) / 256;
  int nb = (N + 2047) / 2048;
  k_wconv<<<128, 256, 0, stream>>>(W0, W1, Wb0, Wb1);
  k_count<<<eb, 256, 0, stream>>>(dst, counts, E);
  k_scan1<<<nb, 256, 0, stream>>>(counts, indptr, bsums, N);
  k_scan2<<<1, 256, 0, stream>>>(bsums, nb);
  k_scan3<<<nb, 256, 0, stream>>>(indptr, cursor, bsums, N);
  k_fill<<<eb, 256, 0, stream>>>(src, dst, cursor, ssort, dsort, E);

  int gb = (N + 127) / 128;
  int mb = (N * 4 + 255) / 256;
  int gb8 = (N + 7) / 8;

  // ---- layer 0 ----
  k_gemm_direct<float, 256><<<gb, 256, 0, stream>>>(x, Wb0, as0, ad0, xp,
                                                    a_src, a_dst, N);
  k_edge<<<eb, 256, 0, stream>>>(ssort, dsort, a_src, a_dst, e_sort, E);
  k_msum<<<mb, 256, 0, stream>>>(e_sort, indptr, counts, m_buf, i_buf, N);
  k_agg<true, ushort><<<gb8, 256, 0, stream>>>(xp, e_sort, ssort, indptr, counts,
                                               m_buf, i_buf, b0, hbuf, N);

  // ---- layer 1 ----
  k_gemm_direct<ushort, 128><<<gb, 256, 0, stream>>>(hbuf, Wb1, as1, ad1, xp,
                                                     a_src, a_dst, N);
  k_edge<<<eb, 256, 0, stream>>>(ssort, dsort, a_src, a_dst, e_sort, E);
  k_msum<<<mb, 256, 0, stream>>>(e_sort, indptr, counts, m_buf, i_buf, N);
  k_agg<false, float><<<gb8, 256, 0, stream>>>(xp, e_sort, ssort, indptr, counts,
                                               m_buf, i_buf, b1, (float*)d_out, N);
}

// Round 6
// 277.301 us; speedup vs baseline: 3.9369x; 1.0724x over previous
//
#include <hip/hip_runtime.h>
#include <hip/hip_bf16.h>
#include <cstdint>
#include <cstddef>
#include <type_traits>

#define SLOPE 0.2f

typedef __attribute__((ext_vector_type(8))) short short8v;
typedef __attribute__((ext_vector_type(4))) float float4v;

__device__ inline ushort f2bf(float f) {
  uint u = __float_as_uint(f);
  uint r = (u + 0x7FFFu + ((u >> 16) & 1u)) >> 16;
  return (ushort)r;
}
__device__ inline float bf2f(ushort u) {
  return __uint_as_float(((uint)u) << 16);
}
__device__ inline float bflo(uint u) { return __uint_as_float(u << 16); }
__device__ inline float bfhi(uint u) { return __uint_as_float(u & 0xffff0000u); }

__device__ inline short8v pack8(float4 a, float4 b) {
  uint4 r;
  r.x = (uint)f2bf(a.x) | ((uint)f2bf(a.y) << 16);
  r.y = (uint)f2bf(a.z) | ((uint)f2bf(a.w) << 16);
  r.z = (uint)f2bf(b.x) | ((uint)f2bf(b.y) << 16);
  r.w = (uint)f2bf(b.z) | ((uint)f2bf(b.w) << 16);
  return __builtin_bit_cast(short8v, r);
}

// ---------------- W pre-conversion (once) ----------------

__global__ void k_wconv(const float* __restrict__ W0, const float* __restrict__ W1,
                        ushort* __restrict__ Wb0, ushort* __restrict__ Wb1) {
  int i = blockIdx.x * 256 + threadIdx.x;
  if (i < 128 * 256) Wb0[i] = f2bf(W0[i]);
  if (i < 128 * 128) Wb1[i] = f2bf(W1[i]);
}

// ---------------- CSR build ----------------

__global__ void k_count(const int* __restrict__ dst, int* __restrict__ counts, int E) {
  int e = blockIdx.x * 256 + threadIdx.x;
  if (e < E) atomicAdd(&counts[dst[e]], 1);
}

__global__ void k_scan1(const int* __restrict__ counts, int* __restrict__ excl,
                        int* __restrict__ bsums, int N) {
  __shared__ int lds[256];
  int tid = threadIdx.x;
  int base = blockIdx.x * 2048 + tid * 8;
  int v[8];
  int ts = 0;
#pragma unroll
  for (int i = 0; i < 8; i++) {
    int idx = base + i;
    int t = (idx < N) ? counts[idx] : 0;
    v[i] = ts;
    ts += t;
  }
  lds[tid] = ts;
  __syncthreads();
  for (int off = 1; off < 256; off <<= 1) {
    int t = (tid >= off) ? lds[tid - off] : 0;
    __syncthreads();
    lds[tid] += t;
    __syncthreads();
  }
  int texcl = (tid > 0) ? lds[tid - 1] : 0;
#pragma unroll
  for (int i = 0; i < 8; i++) {
    int idx = base + i;
    if (idx < N) excl[idx] = texcl + v[i];
  }
  if (tid == 255) bsums[blockIdx.x] = lds[255];
}

__global__ void k_scan2(int* bsums, int nb) {
  __shared__ int lds[256];
  int tid = threadIdx.x;
  int v = (tid < nb) ? bsums[tid] : 0;
  lds[tid] = v;
  __syncthreads();
  for (int off = 1; off < 256; off <<= 1) {
    int t = (tid >= off) ? lds[tid - off] : 0;
    __syncthreads();
    lds[tid] += t;
    __syncthreads();
  }
  if (tid < nb) bsums[tid] = (tid > 0) ? lds[tid - 1] : 0;
}

__global__ void k_scan3(int* __restrict__ excl, int* __restrict__ cursor,
                        const int* __restrict__ bsums, int N) {
  int tid = threadIdx.x;
  int off = bsums[blockIdx.x];
  int base = blockIdx.x * 2048 + tid * 8;
#pragma unroll
  for (int i = 0; i < 8; i++) {
    int idx = base + i;
    if (idx < N) {
      int val = excl[idx] + off;
      excl[idx] = val;
      cursor[idx] = val;
    }
  }
}

__global__ void k_fill(const int* __restrict__ src, const int* __restrict__ dst,
                       int* __restrict__ cursor,
                       int* __restrict__ src_sorted, int* __restrict__ dst_sorted,
                       int E) {
  int e = blockIdx.x * 256 + threadIdx.x;
  if (e < E) {
    int d = dst[e];
    int pos = atomicAdd(&cursor[d], 1);
    src_sorted[pos] = src[e];
    dst_sorted[pos] = d;
  }
}

// ---------------- MFMA GEMM: W staged to LDS once, A global->reg ----------
// C[M,128] = A[M,K] @ Wb[128,K]^T  (Wb pre-converted bf16)
// One barrier total; K-loop has no syncs. Epilogue fuses a_src/a_dst.

template <typename AT, int K>
__global__ __launch_bounds__(256, 2) void k_gemm_lds(
    const AT* __restrict__ A, const ushort* __restrict__ Wb,
    const float* __restrict__ att_src, const float* __restrict__ att_dst,
    ushort* __restrict__ C, float* __restrict__ a_src, float* __restrict__ a_dst,
    int M) {
  constexpr int LDW = K + 8;           // pad: row stride 2*(K+8) B, 16B-aligned
  __shared__ ushort Ws[128 * LDW];
  const int tid = threadIdx.x;
  const int wave = tid >> 6, lane = tid & 63;
  const int fr = lane & 15, fq = lane >> 4;
  const int bm = blockIdx.x * 128;
  const int r0 = bm + wave * 32 + fr;
  const int r1 = r0 + 16;
  const int rc0 = min(r0, M - 1), rc1 = min(r1, M - 1);

  // stage W (128 x K bf16) into padded LDS; each thread copies K/2 ushorts
  {
    int r = tid >> 1, cb = (tid & 1) * (K / 2);
    const ushort* wp = Wb + (size_t)r * K + cb;
    ushort* dp = &Ws[r * LDW + cb];
#pragma unroll
    for (int i = 0; i < K / 16; i++)
      *(uint4*)(dp + i * 8) = *(const uint4*)(wp + i * 8);
  }
  __syncthreads();

  float4v acc[2][8] = {};
#pragma unroll
  for (int k0 = 0; k0 < K; k0 += 32) {
    short8v af0, af1;
    if constexpr (std::is_same<AT, float>::value) {
      const float* p0 = A + (size_t)rc0 * K + k0 + fq * 8;
      const float* p1 = A + (size_t)rc1 * K + k0 + fq * 8;
      af0 = pack8(*(const float4*)p0, *(const float4*)(p0 + 4));
      af1 = pack8(*(const float4*)p1, *(const float4*)(p1 + 4));
    } else {
      af0 = *(const short8v*)(A + (size_t)rc0 * K + k0 + fq * 8);
      af1 = *(const short8v*)(A + (size_t)rc1 * K + k0 + fq * 8);
    }
    short8v bfr[8];
#pragma unroll
    for (int t = 0; t < 8; t++)
      bfr[t] = *(const short8v*)&Ws[(t * 16 + fr) * LDW + k0 + fq * 8];
#pragma unroll
    for (int t = 0; t < 8; t++)
      acc[0][t] = __builtin_amdgcn_mfma_f32_16x16x32_bf16(af0, bfr[t], acc[0][t], 0, 0, 0);
#pragma unroll
    for (int t = 0; t < 8; t++)
      acc[1][t] = __builtin_amdgcn_mfma_f32_16x16x32_bf16(af1, bfr[t], acc[1][t], 0, 0, 0);
  }

  // att coefficients for this lane's columns (t*16+fr)
  float asc[8], adc[8];
#pragma unroll
  for (int t = 0; t < 8; t++) {
    asc[t] = att_src[t * 16 + fr];
    adc[t] = att_dst[t * 16 + fr];
  }

#pragma unroll
  for (int s = 0; s < 2; s++) {
#pragma unroll
    for (int j = 0; j < 4; j++) {
      int row = bm + wave * 32 + s * 16 + fq * 4 + j;
      bool ok = row < M;
      if (ok) {
#pragma unroll
        for (int t = 0; t < 8; t++)
          C[(size_t)row * 128 + t * 16 + fr] = f2bf(acc[s][t][j]);
      }
      float ps[4], pd[4];
#pragma unroll
      for (int h = 0; h < 4; h++) {
        ps[h] = acc[s][2 * h][j] * asc[2 * h] + acc[s][2 * h + 1][j] * asc[2 * h + 1];
        pd[h] = acc[s][2 * h][j] * adc[2 * h] + acc[s][2 * h + 1][j] * adc[2 * h + 1];
      }
#pragma unroll
      for (int off = 1; off < 16; off <<= 1) {
#pragma unroll
        for (int h = 0; h < 4; h++) {
          ps[h] += __shfl_xor(ps[h], off);
          pd[h] += __shfl_xor(pd[h], off);
        }
      }
      if (ok && fr == 0) {
        *(float4*)&a_src[(size_t)row * 4] = make_float4(ps[0], ps[1], ps[2], ps[3]);
        *(float4*)&a_dst[(size_t)row * 4] = make_float4(pd[0], pd[1], pd[2], pd[3]);
      }
    }
  }
}

// ---------------- per-position logits (leaky-relu applied) ----------------

__global__ void k_edge(const int* __restrict__ ss, const int* __restrict__ ds,
                       const float* __restrict__ a_src, const float* __restrict__ a_dst,
                       float* __restrict__ e_sorted, int E) {
  int p = blockIdx.x * 256 + threadIdx.x;
  if (p >= E) return;
  int s = ss[p], d = ds[p];
  float4 as4 = *(const float4*)&a_src[s * 4];
  float4 ad4 = *(const float4*)&a_dst[d * 4];
  float4 ev;
  ev.x = as4.x + ad4.x; ev.x = (ev.x > 0.f) ? ev.x : SLOPE * ev.x;
  ev.y = as4.y + ad4.y; ev.y = (ev.y > 0.f) ? ev.y : SLOPE * ev.y;
  ev.z = as4.z + ad4.z; ev.z = (ev.z > 0.f) ? ev.z : SLOPE * ev.z;
  ev.w = as4.w + ad4.w; ev.w = (ev.w > 0.f) ? ev.w : SLOPE * ev.w;
  *(float4*)&e_sorted[p * 4] = ev;
}

// ---------------- per-(node,head) softmax stats: m, 1/(s+eps) ----------------

__global__ __launch_bounds__(256) void k_msum(const float* __restrict__ e_sorted,
                                              const int* __restrict__ indptr,
                                              const int* __restrict__ counts,
                                              float* __restrict__ m_buf,
                                              float* __restrict__ inv_buf, int N) {
  int t = blockIdx.x * 256 + threadIdx.x;
  int n = t >> 2, h = t & 3;
  if (n >= N) return;
  int deg = counts[n], start = indptr[n];
  const float* eb = e_sorted + (size_t)start * 4 + h;
  float m0 = -INFINITY, m1 = -INFINITY, m2 = -INFINITY, m3 = -INFINITY;
  int i = 0;
  for (; i + 4 <= deg; i += 4) {
    float a = eb[(i + 0) * 4], b = eb[(i + 1) * 4];
    float c = eb[(i + 2) * 4], d = eb[(i + 3) * 4];
    m0 = fmaxf(m0, a); m1 = fmaxf(m1, b); m2 = fmaxf(m2, c); m3 = fmaxf(m3, d);
  }
  for (; i < deg; i++) m0 = fmaxf(m0, eb[i * 4]);
  float m = fmaxf(fmaxf(m0, m1), fmaxf(m2, m3));
  float s = 0.f;
  i = 0;
  for (; i + 4 <= deg; i += 4) {
    float a = eb[(i + 0) * 4], b = eb[(i + 1) * 4];
    float c = eb[(i + 2) * 4], d = eb[(i + 3) * 4];
    s += __expf(a - m) + __expf(b - m) + __expf(c - m) + __expf(d - m);
  }
  for (; i < deg; i++) s += __expf(eb[i * 4] - m);
  m_buf[t] = m;
  inv_buf[t] = 1.f / (s + 1e-16f);
}

// ---------------- aggregation: 32 threads/node, 4 channels/thread ----------------

template <bool RELU, typename OT>
__global__ __launch_bounds__(256) void k_agg(const ushort* __restrict__ xp,
                                             const float* __restrict__ e_sorted,
                                             const int* __restrict__ src_sorted,
                                             const int* __restrict__ indptr,
                                             const int* __restrict__ counts,
                                             const float* __restrict__ m_buf,
                                             const float* __restrict__ inv_buf,
                                             const float* __restrict__ bias,
                                             OT* __restrict__ out, int N) {
  int tid = threadIdx.x;
  int n = blockIdx.x * 8 + (tid >> 5);
  if (n >= N) return;
  int c4 = tid & 31;          // channel group: channels 4*c4 .. 4*c4+3
  int h = c4 >> 3;
  int deg = counts[n];
  int start = indptr[n];
  const float* eb = e_sorted + (size_t)start * 4 + h;
  const int* sp = src_sorted + start;
  const ushort* xpc = xp + c4 * 4;
  float m = m_buf[n * 4 + h];
  float inv = inv_buf[n * 4 + h];

  float a0 = 0.f, a1 = 0.f, a2 = 0.f, a3 = 0.f;
  int i = 0;
  for (; i + 4 <= deg; i += 4) {
    int s0 = sp[i], s1 = sp[i + 1], s2 = sp[i + 2], s3 = sp[i + 3];
    float e0 = eb[(i + 0) * 4], e1 = eb[(i + 1) * 4];
    float e2 = eb[(i + 2) * 4], e3 = eb[(i + 3) * 4];
    uint2 v0 = *(const uint2*)(xpc + (size_t)s0 * 128);
    uint2 v1 = *(const uint2*)(xpc + (size_t)s1 * 128);
    uint2 v2 = *(const uint2*)(xpc + (size_t)s2 * 128);
    uint2 v3 = *(const uint2*)(xpc + (size_t)s3 * 128);
    float x0 = __expf(e0 - m), x1 = __expf(e1 - m);
    float x2 = __expf(e2 - m), x3 = __expf(e3 - m);
    a0 = fmaf(bflo(v0.x), x0, a0); a1 = fmaf(bfhi(v0.x), x0, a1);
    a2 = fmaf(bflo(v0.y), x0, a2); a3 = fmaf(bfhi(v0.y), x0, a3);
    a0 = fmaf(bflo(v1.x), x1, a0); a1 = fmaf(bfhi(v1.x), x1, a1);
    a2 = fmaf(bflo(v1.y), x1, a2); a3 = fmaf(bfhi(v1.y), x1, a3);
    a0 = fmaf(bflo(v2.x), x2, a0); a1 = fmaf(bfhi(v2.x), x2, a1);
    a2 = fmaf(bflo(v2.y), x2, a2); a3 = fmaf(bfhi(v2.y), x2, a3);
    a0 = fmaf(bflo(v3.x), x3, a0); a1 = fmaf(bfhi(v3.x), x3, a1);
    a2 = fmaf(bflo(v3.y), x3, a2); a3 = fmaf(bfhi(v3.y), x3, a3);
  }
  for (; i < deg; i++) {
    int s0 = sp[i];
    float x0 = __expf(eb[i * 4] - m);
    uint2 v0 = *(const uint2*)(xpc + (size_t)s0 * 128);
    a0 = fmaf(bflo(v0.x), x0, a0); a1 = fmaf(bfhi(v0.x), x0, a1);
    a2 = fmaf(bflo(v0.y), x0, a2); a3 = fmaf(bfhi(v0.y), x0, a3);
  }

  float4 bv = *(const float4*)&bias[c4 * 4];
  float o0 = fmaf(a0, inv, bv.x);
  float o1 = fmaf(a1, inv, bv.y);
  float o2 = fmaf(a2, inv, bv.z);
  float o3 = fmaf(a3, inv, bv.w);
  if (RELU) {
    o0 = fmaxf(o0, 0.f); o1 = fmaxf(o1, 0.f);
    o2 = fmaxf(o2, 0.f); o3 = fmaxf(o3, 0.f);
  }
  if constexpr (std::is_same<OT, float>::value) {
    *(float4*)&out[(size_t)n * 128 + c4 * 4] = make_float4(o0, o1, o2, o3);
  } else {
    uint2 pk;
    pk.x = (uint)f2bf(o0) | ((uint)f2bf(o1) << 16);
    pk.y = (uint)f2bf(o2) | ((uint)f2bf(o3) << 16);
    *(uint2*)&((ushort*)out)[(size_t)n * 128 + c4 * 4] = pk;
  }
}

// ---------------- launch ----------------

extern "C" void kernel_launch(void* const* d_in, const int* in_sizes, int n_in,
                              void* d_out, int out_size, void* d_ws, size_t ws_size,
                              hipStream_t stream) {
  const float* x   = (const float*)d_in[0];
  const int*   ei  = (const int*)d_in[1];
  const float* W0  = (const float*)d_in[2];
  const float* as0 = (const float*)d_in[3];
  const float* ad0 = (const float*)d_in[4];
  const float* b0  = (const float*)d_in[5];
  const float* W1  = (const float*)d_in[6];
  const float* as1 = (const float*)d_in[7];
  const float* ad1 = (const float*)d_in[8];
  const float* b1  = (const float*)d_in[9];

  const int N = in_sizes[0] / 256;   // 100000
  const int E = in_sizes[1] / 2;     // 800000
  const int* src = ei;
  const int* dst = ei + E;

  char* ws = (char*)d_ws;
  size_t off = 0;
  auto alloc = [&](size_t bytes) -> void* {
    void* p = ws + off;
    off += (bytes + 255) & ~(size_t)255;
    return p;
  };
  ushort* xp    = (ushort*)alloc((size_t)N * 128 * 2);
  ushort* hbuf  = (ushort*)alloc((size_t)N * 128 * 2);
  float* a_src  = (float*)alloc((size_t)N * 4 * 4);
  float* a_dst  = (float*)alloc((size_t)N * 4 * 4);
  float* e_sort = (float*)alloc((size_t)E * 4 * 4);
  float* m_buf  = (float*)alloc((size_t)N * 4 * 4);
  float* i_buf  = (float*)alloc((size_t)N * 4 * 4);
  int*   counts = (int*)alloc((size_t)N * 4);
  int*   indptr = (int*)alloc((size_t)N * 4);
  int*   cursor = (int*)alloc((size_t)N * 4);
  int*   ssort  = (int*)alloc((size_t)E * 4);
  int*   dsort  = (int*)alloc((size_t)E * 4);
  int*   bsums  = (int*)alloc(256 * 4);
  ushort* Wb0   = (ushort*)alloc((size_t)128 * 256 * 2);
  ushort* Wb1   = (ushort*)alloc((size_t)128 * 128 * 2);

  // ---- W conversion + CSR build (by dst) ----
  hipMemsetAsync(counts, 0, (size_t)N * 4, stream);
  int eb = (E + 255) / 256;
  int nb = (N + 2047) / 2048;
  k_wconv<<<128, 256, 0, stream>>>(W0, W1, Wb0, Wb1);
  k_count<<<eb, 256, 0, stream>>>(dst, counts, E);
  k_scan1<<<nb, 256, 0, stream>>>(counts, indptr, bsums, N);
  k_scan2<<<1, 256, 0, stream>>>(bsums, nb);
  k_scan3<<<nb, 256, 0, stream>>>(indptr, cursor, bsums, N);
  k_fill<<<eb, 256, 0, stream>>>(src, dst, cursor, ssort, dsort, E);

  int gb = (N + 127) / 128;
  int mb = (N * 4 + 255) / 256;
  int gb8 = (N + 7) / 8;

  // ---- layer 0 ----
  k_gemm_lds<float, 256><<<gb, 256, 0, stream>>>(x, Wb0, as0, ad0, xp,
                                                 a_src, a_dst, N);
  k_edge<<<eb, 256, 0, stream>>>(ssort, dsort, a_src, a_dst, e_sort, E);
  k_msum<<<mb, 256, 0, stream>>>(e_sort, indptr, counts, m_buf, i_buf, N);
  k_agg<true, ushort><<<gb8, 256, 0, stream>>>(xp, e_sort, ssort, indptr, counts,
                                               m_buf, i_buf, b0, hbuf, N);

  // ---- layer 1 ----
  k_gemm_lds<ushort, 128><<<gb, 256, 0, stream>>>(hbuf, Wb1, as1, ad1, xp,
                                                  a_src, a_dst, N);
  k_edge<<<eb, 256, 0, stream>>>(ssort, dsort, a_src, a_dst, e_sort, E);
  k_msum<<<mb, 256, 0, stream>>>(e_sort, indptr, counts, m_buf, i_buf, N);
  k_agg<false, float><<<gb8, 256, 0, stream>>>(xp, e_sort, ssort, indptr, counts,
                                               m_buf, i_buf, b1, (float*)d_out, N);
}